// Round 1
// baseline (10260.831 us; speedup 1.0000x reference)
//
#include <hip/hip_runtime.h>
#include <math.h>

#define NBATCH 2
#define TT 4
#define DD 768
#define DI_ 1536
#define NS_ 16
#define RK_ 48
#define KC_ 4
#define DEPTH_ 16
#define LV 448          // visible tokens
#define NROWS (NBATCH*LV)   // 896

__device__ __forceinline__ float silu_f(float x) { return x / (1.f + __expf(-x)); }

// ---------------- generic fp32 GEMM: C[M,N] = A[M,(lda)] * W[N,(ldw)]^T ------------
// optional split-K (gridDim.z>1): each z-block writes its own partial buffer slice.
// epi: 0 = +bias (if bias), 1 = softplus(acc + bias)
__global__ __launch_bounds__(256) void gemm_nt(
    const float* __restrict__ A, int lda,
    const float* __restrict__ W, int ldw,
    const float* __restrict__ bias,
    float* __restrict__ C, int ldc,
    int M, int N, int K, int kChunk, long partStride, int epi)
{
  __shared__ float As[16][68];
  __shared__ float Ws[16][68];
  int tid = threadIdx.x;
  int m0 = blockIdx.y * 64;
  int n0 = blockIdx.x * 64;
  int kbeg = 0, kend = K;
  if (gridDim.z > 1) {
    kbeg = blockIdx.z * kChunk;
    kend = min(K, kbeg + kChunk);
    C += (long)blockIdx.z * partStride;
  }
  int ty = tid >> 4, tx = tid & 15;
  float acc[4][4] = {};
  for (int k0 = kbeg; k0 < kend; k0 += 16) {
#pragma unroll
    for (int i = 0; i < 4; ++i) {
      int idx = tid + i * 256;
      int mm = idx >> 4, kk = idx & 15;
      int gm = m0 + mm, gk = k0 + kk;
      As[kk][mm] = (gm < M && gk < kend) ? A[(size_t)gm * lda + gk] : 0.f;
      int gn = n0 + mm;
      Ws[kk][mm] = (gn < N && gk < kend) ? W[(size_t)gn * ldw + gk] : 0.f;
    }
    __syncthreads();
#pragma unroll
    for (int kk = 0; kk < 16; ++kk) {
      float a[4], b[4];
#pragma unroll
      for (int i = 0; i < 4; ++i) a[i] = As[kk][ty * 4 + i];
#pragma unroll
      for (int j = 0; j < 4; ++j) b[j] = Ws[kk][tx * 4 + j];
#pragma unroll
      for (int i = 0; i < 4; ++i)
#pragma unroll
        for (int j = 0; j < 4; ++j) acc[i][j] = fmaf(a[i], b[j], acc[i][j]);
    }
    __syncthreads();
  }
#pragma unroll
  for (int i = 0; i < 4; ++i) {
    int gm = m0 + ty * 4 + i;
    if (gm >= M) continue;
#pragma unroll
    for (int j = 0; j < 4; ++j) {
      int gn = n0 + tx * 4 + j;
      if (gn >= N) continue;
      float v = acc[i][j];
      if (bias) v += bias[gn];
      if (epi == 1) v = (v > 20.f) ? v : log1pf(__expf(v));
      C[(size_t)gm * ldc + gn] = v;
    }
  }
}

// ---------------- split-K reduce ----------------
__global__ __launch_bounds__(256) void reduce_k(const float* __restrict__ part,
                                                float* __restrict__ out, int nc, int n)
{
  int i = blockIdx.x * 256 + threadIdx.x;
  if (i >= n) return;
  float s = 0.f;
  for (int c = 0; c < nc; ++c) s += part[(size_t)c * n + i];
  out[i] = s;
}

// ---------------- im2col video: A[1568][768], k = c*256 + kh*16 + kw ----------------
__global__ __launch_bounds__(256) void im2col_v(const float* __restrict__ xv, float* __restrict__ Av)
{
  int i = blockIdx.x * 256 + threadIdx.x;
  if (i >= 1568 * 768) return;
  int m = i / 768, k = i % 768;
  int c = k >> 8, r = k & 255;
  int kh = r >> 4, kw = r & 15;
  int bt = m / 196, n = m % 196;
  int b = bt / TT, t = bt % TT;
  int hb = n / 14, wb = n % 14;
  Av[i] = xv[(size_t)b * 602112 + (size_t)c * 200704 + t * 50176 + (hb * 16 + kh) * 224 + wb * 16 + kw];
}

// ---------------- im2col audio: A[192][256], m = b*96 + tb*4 + fb, k = kh*16+kw ------
__global__ __launch_bounds__(256) void im2col_a(const float* __restrict__ xa, float* __restrict__ Aa)
{
  int i = blockIdx.x * 256 + threadIdx.x;
  if (i >= 192 * 256) return;
  int m = i / 256, k = i % 256;
  int kh = k >> 4, kw = k & 15;
  int b = m / 96, q = m % 96;
  int tb = q >> 2, fb = q & 3;
  Aa[i] = xa[(size_t)b * 24576 + (fb * 16 + kw) * 384 + tb * 16 + kh];
}

// ---------------- assemble tokens + gather visible -> h ; res = 0 ----------------
__global__ __launch_bounds__(256) void assemble_k(
    const float* __restrict__ tokv, const float* __restrict__ toka,
    const float* __restrict__ pos_v, const float* __restrict__ pos_a,
    const float* __restrict__ tpos_v, const float* __restrict__ tpos_a,
    const float* __restrict__ cls_v, const float* __restrict__ cls_a,
    const float* __restrict__ glob_v, const float* __restrict__ glob_a,
    const int* __restrict__ vis_idx,
    float* __restrict__ h, float* __restrict__ res)
{
  int i = blockIdx.x * 256 + threadIdx.x;
  if (i >= NROWS * DD) return;
  int d = i % DD;
  int bl = i / DD;
  int r = bl % LV, b = bl / LV;
  int tok = vis_idx[b * LV + r];
  int t = tok / 224, q = tok % 224;
  float v;
  if (q == 0) v = cls_v[d];
  else if (q <= 196) {
    int n = q - 1;
    v = tokv[((size_t)(b * TT + t) * 196 + n) * DD + d] + pos_v[n * DD + d] + tpos_v[t * DD + d];
  } else if (q == 197) v = glob_v[d];
  else if (q == 198) v = cls_a[d];
  else if (q <= 222) {
    int n = q - 199;
    v = toka[((size_t)b * 96 + t * 24 + n) * DD + d] + pos_a[n * DD + d] + tpos_a[t * DD + d];
  } else v = glob_a[d];
  h[i] = v;
  res[i] = 0.f;
}

// ---------------- fused residual add + RMSNorm ----------------
__global__ __launch_bounds__(256) void rmsnorm_k(
    const float* __restrict__ h, float* __restrict__ res,
    float* __restrict__ hn, const float* __restrict__ nw)
{
  int row = blockIdx.x;
  const float* hp = h + (size_t)row * DD;
  float* rp = res + (size_t)row * DD;
  float* op = hn + (size_t)row * DD;
  int tid = threadIdx.x;
  float v[3];
  float ss = 0.f;
#pragma unroll
  for (int i = 0; i < 3; ++i) {
    float x = hp[tid + i * 256] + rp[tid + i * 256];
    v[i] = x;
    ss += x * x;
  }
  for (int m = 1; m < 64; m <<= 1) ss += __shfl_xor(ss, m, 64);
  __shared__ float sred[4];
  if ((tid & 63) == 0) sred[tid >> 6] = ss;
  __syncthreads();
  float tot = sred[0] + sred[1] + sred[2] + sred[3];
  float sc = rsqrtf(tot / (float)DD + 1e-5f);
#pragma unroll
  for (int i = 0; i < 3; ++i) {
    int c = tid + i * 256;
    rp[c] = v[i];
    op[c] = v[i] * sc * nw[c];
  }
}

// ---------------- causal depthwise conv (k=4) + silu, fwd + reversed ----------------
__global__ __launch_bounds__(256) void conv_k(
    const float* __restrict__ xz,
    const float* __restrict__ cw, const float* __restrict__ cb,
    const float* __restrict__ cwb, const float* __restrict__ cbb,
    float* __restrict__ xcF, float* __restrict__ xcB)
{
  int i = blockIdx.x * 256 + threadIdx.x;
  if (i >= NROWS * DI_) return;
  int d = i % DI_;
  int bl = i / DI_;
  int l = bl % LV, b = bl / LV;
  const float* xzb = xz + (size_t)b * LV * (2 * DI_);
  float accf = cb[d];
#pragma unroll
  for (int j = 0; j < 4; ++j) {
    int lp = l - 3 + j;
    if (lp >= 0) accf += xzb[(size_t)lp * (2 * DI_) + d] * cw[d * 4 + j];
  }
  float accb = cbb[d];
#pragma unroll
  for (int j = 0; j < 4; ++j) {
    int lp = l - 3 + j;
    if (lp >= 0) accb += xzb[(size_t)(LV - 1 - lp) * (2 * DI_) + d] * cwb[d * 4 + j];
  }
  xcF[i] = silu_f(accf);
  xcB[i] = silu_f(accb);
}

// ---------------- selective scan: 16 lanes per (b,d), one lane per state n -------
__global__ __launch_bounds__(256) void scan_k(
    const float* __restrict__ xcF, const float* __restrict__ dtF, const float* __restrict__ prF,
    const float* __restrict__ xcB, const float* __restrict__ dtB, const float* __restrict__ prB,
    const float* __restrict__ AlF, const float* __restrict__ AlB,
    const float* __restrict__ DpF, const float* __restrict__ DpB,
    float* __restrict__ yF, float* __restrict__ yB)
{
  int dir = blockIdx.y;
  const float* xc = dir ? xcB : xcF;
  const float* dt = dir ? dtB : dtF;
  const float* pr = dir ? prB : prF;
  const float* Al = dir ? AlB : AlF;
  const float* Dpp = dir ? DpB : DpF;
  float* y = dir ? yB : yF;

  int g = blockIdx.x * 16 + (threadIdx.x >> 4);
  int n = threadIdx.x & 15;
  int b = g / DI_, d = g % DI_;
  float An = -__expf(Al[d * NS_ + n]);
  float Dpd = Dpp[d];
  float hs = 0.f;
  const float* xcp = xc + (size_t)b * LV * DI_ + d;
  const float* dtp = dt + (size_t)b * LV * DI_ + d;
  const float* prp = pr + (size_t)b * LV * 80;
  float* yp = y + (size_t)b * LV * DI_ + d;

  float dtv = dtp[0];
  float xcv = xcp[0];
  float bn = prp[48 + n];
  float cn = prp[64 + n];
  for (int l = 0; l < LV; ++l) {
    float dtv_n = 0.f, xcv_n = 0.f, bn_n = 0.f, cn_n = 0.f;
    if (l + 1 < LV) {
      dtv_n = dtp[(size_t)(l + 1) * DI_];
      xcv_n = xcp[(size_t)(l + 1) * DI_];
      bn_n = prp[(l + 1) * 80 + 48 + n];
      cn_n = prp[(l + 1) * 80 + 64 + n];
    }
    hs = __expf(dtv * An) * hs + dtv * bn * xcv;
    float p = hs * cn;
    p += __shfl_xor(p, 1, 16);
    p += __shfl_xor(p, 2, 16);
    p += __shfl_xor(p, 4, 16);
    p += __shfl_xor(p, 8, 16);
    if (n == 0) yp[(size_t)l * DI_] = p + xcv * Dpd;
    dtv = dtv_n; xcv = xcv_n; bn = bn_n; cn = cn_n;
  }
}

// ---------------- combine: (yf[l] + yb[L-1-l]) * silu(zi[l]) ----------------
__global__ __launch_bounds__(256) void combine_k(
    const float* __restrict__ yF, const float* __restrict__ yB,
    const float* __restrict__ xz, float* __restrict__ yc)
{
  int i = blockIdx.x * 256 + threadIdx.x;
  if (i >= NROWS * DI_) return;
  int d = i % DI_;
  int bl = i / DI_;
  int l = bl % LV, b = bl / LV;
  float z = xz[(size_t)(b * LV + l) * (2 * DI_) + DI_ + d];
  float v = (yF[i] + yB[((size_t)b * LV + (LV - 1 - l)) * DI_ + d]) * silu_f(z);
  yc[i] = v;
}

__global__ __launch_bounds__(256) void copy_k(const float* __restrict__ src, float* __restrict__ dst, int n)
{
  int i = blockIdx.x * 256 + threadIdx.x;
  if (i < n) dst[i] = src[i];
}

extern "C" void kernel_launch(void* const* d_in, const int* in_sizes, int n_in,
                              void* d_out, int out_size, void* d_ws, size_t ws_size,
                              hipStream_t stream)
{
  const float* x_v = (const float*)d_in[0];
  const float* x_a = (const float*)d_in[1];
  const float* patch_v_w = (const float*)d_in[2];
  const float* patch_v_b = (const float*)d_in[3];
  const float* patch_a_w = (const float*)d_in[4];
  const float* patch_a_b = (const float*)d_in[5];
  const float* pos_v = (const float*)d_in[6];
  const float* pos_a = (const float*)d_in[7];
  const float* tpos_v = (const float*)d_in[8];
  const float* tpos_a = (const float*)d_in[9];
  const float* cls_v = (const float*)d_in[10];
  const float* cls_a = (const float*)d_in[11];
  const float* glob_v = (const float*)d_in[12];
  const float* glob_a = (const float*)d_in[13];
  const float* norm_w = (const float*)d_in[14];
  const float* in_w = (const float*)d_in[15];
  const float* conv_w = (const float*)d_in[16];
  const float* conv_b = (const float*)d_in[17];
  const float* conv_w_b = (const float*)d_in[18];
  const float* conv_b_b = (const float*)d_in[19];
  const float* xproj_w = (const float*)d_in[20];
  const float* xproj_w_b = (const float*)d_in[21];
  // dict order vs signature order disambiguation for dt_w_b / dt_b
  const float *dt_w, *dt_bias, *dt_w_b, *dt_bias_b;
  if (in_sizes[23] == DEPTH_ * DI_ * RK_) {  // dict order: 22=dt_w 23=dt_w_b 24=dt_b 25=dt_b_b
    dt_w = (const float*)d_in[22]; dt_w_b = (const float*)d_in[23];
    dt_bias = (const float*)d_in[24]; dt_bias_b = (const float*)d_in[25];
  } else {                                    // signature order: 22=dt_w 23=dt_b 24=dt_w_b 25=dt_b_b
    dt_w = (const float*)d_in[22]; dt_bias = (const float*)d_in[23];
    dt_w_b = (const float*)d_in[24]; dt_bias_b = (const float*)d_in[25];
  }
  const float* A_log = (const float*)d_in[26];
  const float* A_log_b = (const float*)d_in[27];
  const float* D_par = (const float*)d_in[28];
  const float* D_par_b = (const float*)d_in[29];
  const float* out_w = (const float*)d_in[30];
  const int* vis_idx = (const int*)d_in[31];

  float* ws = (float*)d_ws;
  float* res = ws;                       // 688128
  float* hbuf = ws + 688128;             // 688128
  float* S = ws + 2 * 688128;
  // phase-1 scratch (overlaps phase-2 scratch)
  float* Av = S;                         // 1204224
  float* Aa = Av + 1204224;              // 49152
  float* tokv = Aa + 49152;              // 1204224
  float* toka = tokv + 1204224;          // 147456
  // phase-2 scratch
  float* hn = S;                         // 688128
  float* xz = hn + 688128;               // 2752512
  float* xcF = xz + 2752512;             // 1376256
  float* xcB = xcF + 1376256;            // 1376256
  float* dtF = xcB + 1376256;            // 1376256
  float* dtB = dtF + 1376256;            // 1376256
  float* projF = dtB + 1376256;          // 71680
  float* projB = projF + 71680;          // 71680
  float* partF = projB + 71680;          // 430080
  float* partB = partF + 430080;         // 430080
  float* yF = partB + 430080;            // 1376256
  float* yB = yF + 1376256;              // 1376256
  float* yc = yB + 1376256;              // 1376256

  dim3 blk(256);

  // ---- phase 1: patch embed + assemble ----
  im2col_v<<<4704, blk, 0, stream>>>(x_v, Av);
  im2col_a<<<192, blk, 0, stream>>>(x_a, Aa);
  gemm_nt<<<dim3(12, 25, 1), blk, 0, stream>>>(Av, 768, patch_v_w, 768, patch_v_b,
                                               tokv, 768, 1568, 768, 768, 0, 0, 0);
  gemm_nt<<<dim3(12, 3, 1), blk, 0, stream>>>(Aa, 256, patch_a_w, 256, patch_a_b,
                                              toka, 768, 192, 768, 256, 0, 0, 0);
  assemble_k<<<2688, blk, 0, stream>>>(tokv, toka, pos_v, pos_a, tpos_v, tpos_a,
                                       cls_v, cls_a, glob_v, glob_a, vis_idx, hbuf, res);

  // ---- phase 2: 16 layers ----
  for (int l = 0; l < DEPTH_; ++l) {
    const float* nw = norm_w + l * DD;
    const float* iw = in_w + (size_t)l * 2 * DI_ * DD;
    const float* cw = conv_w + l * DI_ * KC_;
    const float* cb = conv_b + l * DI_;
    const float* cwb = conv_w_b + l * DI_ * KC_;
    const float* cbb = conv_b_b + l * DI_;
    const float* xw = xproj_w + (size_t)l * 80 * DI_;
    const float* xwb = xproj_w_b + (size_t)l * 80 * DI_;
    const float* dw = dt_w + (size_t)l * DI_ * RK_;
    const float* dbi = dt_bias + l * DI_;
    const float* dwb = dt_w_b + (size_t)l * DI_ * RK_;
    const float* dbib = dt_bias_b + l * DI_;
    const float* al = A_log + (size_t)l * DI_ * NS_;
    const float* alb = A_log_b + (size_t)l * DI_ * NS_;
    const float* dp = D_par + l * DI_;
    const float* dpb = D_par_b + l * DI_;
    const float* ow = out_w + (size_t)l * DD * DI_;

    rmsnorm_k<<<NROWS, blk, 0, stream>>>(hbuf, res, hn, nw);
    gemm_nt<<<dim3(48, 14, 1), blk, 0, stream>>>(hn, 768, iw, 768, nullptr,
                                                 xz, 3072, NROWS, 3072, 768, 0, 0, 0);
    conv_k<<<5376, blk, 0, stream>>>(xz, cw, cb, cwb, cbb, xcF, xcB);
    // xproj GEMMs: split-K (K=1536 -> 6 chunks of 256), deterministic partials
    gemm_nt<<<dim3(2, 14, 6), blk, 0, stream>>>(xcF, 1536, xw, 1536, nullptr,
                                                partF, 80, NROWS, 80, 1536, 256, 71680, 0);
    gemm_nt<<<dim3(2, 14, 6), blk, 0, stream>>>(xcB, 1536, xwb, 1536, nullptr,
                                                partB, 80, NROWS, 80, 1536, 256, 71680, 0);
    reduce_k<<<280, blk, 0, stream>>>(partF, projF, 6, 71680);
    reduce_k<<<280, blk, 0, stream>>>(partB, projB, 6, 71680);
    // dt GEMM + fused bias + softplus
    gemm_nt<<<dim3(24, 14, 1), blk, 0, stream>>>(projF, 80, dw, 48, dbi,
                                                 dtF, 1536, NROWS, 1536, 48, 0, 0, 1);
    gemm_nt<<<dim3(24, 14, 1), blk, 0, stream>>>(projB, 80, dwb, 48, dbib,
                                                 dtB, 1536, NROWS, 1536, 48, 0, 0, 1);
    scan_k<<<dim3(192, 2, 1), blk, 0, stream>>>(xcF, dtF, projF, xcB, dtB, projB,
                                                al, alb, dp, dpb, yF, yB);
    combine_k<<<5376, blk, 0, stream>>>(yF, yB, xz, yc);
    gemm_nt<<<dim3(12, 14, 1), blk, 0, stream>>>(yc, 1536, ow, 1536, nullptr,
                                                 hbuf, 768, NROWS, 768, 1536, 0, 0, 0);
  }

  copy_k<<<2688, blk, 0, stream>>>(res, (float*)d_out, out_size);
}

// Round 2
// 5048.562 us; speedup vs baseline: 2.0324x; 2.0324x over previous
//
#include <hip/hip_runtime.h>
#include <math.h>

typedef unsigned short ushort_t;
typedef __attribute__((ext_vector_type(8))) short bf16x8;
typedef __attribute__((ext_vector_type(4))) float f32x4;

#define NBATCH 2
#define TT 4
#define DD 768
#define DI_ 1536
#define NS_ 16
#define RK_ 48
#define KC_ 4
#define DEPTH_ 16
#define LV 448
#define NROWS (NBATCH*LV)   // 896

__device__ __forceinline__ float silu_f(float x) { return x / (1.f + __expf(-x)); }
__device__ __forceinline__ ushort_t f2bf(float x) {
  unsigned int u = __float_as_uint(x);
  return (ushort_t)((u + 0x7FFFu + ((u >> 16) & 1u)) >> 16);
}
__device__ __forceinline__ float bf2f(ushort_t h) {
  return __uint_as_float(((unsigned int)h) << 16);
}

typedef const __attribute__((address_space(1))) unsigned int* gas1_t;
typedef __attribute__((address_space(3))) unsigned int* las3_t;
__device__ __forceinline__ void gll16(const ushort_t* g, ushort_t* l) {
  __builtin_amdgcn_global_load_lds((gas1_t)g, (las3_t)l, 16, 0, 0);
}

// ===================== bf16 MFMA GEMM: C[M,N] = A[M,K] @ W[N,K]^T ==============
// 128x128 tile, 4 waves, BK=32, 16x16x32_bf16. LDS staged via global_load_lds w=16
// with source-side XOR swizzle (slot group ^= (row>>1)&3) matched at ds_read.
// z = dir*nkChunks + chunk. dir==1 switches to A2/W2/C2/bias2. Split-K writes
// per-chunk partials at C + chunk*partStride (deterministic).
// epi: 0 = (+bias), 1 = softplus(acc+bias)
__global__ __launch_bounds__(256) void mfma_gemm(
    const ushort_t* __restrict__ A, const ushort_t* __restrict__ A2, int lda,
    const ushort_t* __restrict__ W, const ushort_t* __restrict__ W2, int ldw,
    const float* __restrict__ bias, const float* __restrict__ bias2,
    float* __restrict__ C, float* __restrict__ C2, int ldc,
    int M, int K, int nkChunks, long partStride, int epi)
{
  int z = blockIdx.z;
  int dir = z / nkChunks, chunk = z - dir * nkChunks;
  if (dir) { A = A2; W = W2; C = C2; bias = bias2; }
  int kChunk = K / nkChunks;
  int kbeg = chunk * kChunk;
  if (nkChunks > 1) C += (long)chunk * partStride;

  __shared__ __align__(16) ushort_t At[128 * 32];
  __shared__ __align__(16) ushort_t Bt[128 * 32];

  int tid = threadIdx.x, wv = tid >> 6, lane = tid & 63;
  int m0 = blockIdx.y * 128, n0 = blockIdx.x * 128;

  // staging: 512 16B-slots per tile; wave w owns slots [w*128, w*128+128)
  int S0 = wv * 128 + lane, S1 = S0 + 64;
  int r0 = S0 >> 2, g0 = (S0 & 3) ^ ((r0 >> 1) & 3);
  int r1 = S1 >> 2, g1 = (S1 & 3) ^ ((r1 >> 1) & 3);
  const ushort_t* a0 = A + (size_t)min(m0 + r0, M - 1) * lda + g0 * 8 + kbeg;
  const ushort_t* a1 = A + (size_t)min(m0 + r1, M - 1) * lda + g1 * 8 + kbeg;
  const ushort_t* b0 = W + (size_t)(n0 + r0) * ldw + g0 * 8 + kbeg;
  const ushort_t* b1 = W + (size_t)(n0 + r1) * ldw + g1 * 8 + kbeg;
  ushort_t* lA0 = At + S0 * 8; ushort_t* lA1 = At + S1 * 8;
  ushort_t* lB0 = Bt + S0 * 8; ushort_t* lB1 = Bt + S1 * 8;

  int wr = wv >> 1, wc = wv & 1;
  int rl = lane & 15, gl = lane >> 4;
  int offA[4], offB[4];
#pragma unroll
  for (int i = 0; i < 4; ++i) {
    int ra = wr * 64 + i * 16 + rl;
    offA[i] = ra * 32 + ((gl ^ ((ra >> 1) & 3)) * 8);
    int rb = wc * 64 + i * 16 + rl;
    offB[i] = rb * 32 + ((gl ^ ((rb >> 1) & 3)) * 8);
  }

  f32x4 acc[4][4] = {};
  int nk = kChunk >> 5;
  for (int t = 0; t < nk; ++t) {
    int ko = t << 5;
    gll16(a0 + ko, lA0); gll16(a1 + ko, lA1);
    gll16(b0 + ko, lB0); gll16(b1 + ko, lB1);
    __syncthreads();   // drains vmcnt before barrier
    bf16x8 af[4], bw[4];
#pragma unroll
    for (int i = 0; i < 4; ++i) {
      af[i] = *(const bf16x8*)(At + offA[i]);
      bw[i] = *(const bf16x8*)(Bt + offB[i]);
    }
#pragma unroll
    for (int i = 0; i < 4; ++i)
#pragma unroll
      for (int j = 0; j < 4; ++j)
        acc[i][j] = __builtin_amdgcn_mfma_f32_16x16x32_bf16(af[i], bw[j], acc[i][j], 0, 0, 0);
    __syncthreads();
  }

  // epilogue: D row=(lane>>4)*4+q, col=lane&15 per 16x16 fragment
#pragma unroll
  for (int i = 0; i < 4; ++i) {
    int row0 = m0 + wr * 64 + i * 16 + gl * 4;
#pragma unroll
    for (int q = 0; q < 4; ++q) {
      int row = row0 + q;
      if (row >= M) continue;
#pragma unroll
      for (int j = 0; j < 4; ++j) {
        int col = n0 + wc * 64 + j * 16 + rl;
        float v = acc[i][j][q];
        if (bias) v += bias[col];
        if (epi == 1) v = (v > 20.f) ? v : log1pf(__expf(v));
        C[(size_t)row * ldc + col] = v;
      }
    }
  }
}

// ===================== fp32 GEMM (audio patch only) =====================
__global__ __launch_bounds__(256) void gemm_nt(
    const float* __restrict__ A, int lda,
    const float* __restrict__ W, int ldw,
    const float* __restrict__ bias,
    float* __restrict__ C, int ldc, int M, int N, int K)
{
  __shared__ float As[16][68];
  __shared__ float Ws[16][68];
  int tid = threadIdx.x;
  int m0 = blockIdx.y * 64, n0 = blockIdx.x * 64;
  int ty = tid >> 4, tx = tid & 15;
  float acc[4][4] = {};
  for (int k0 = 0; k0 < K; k0 += 16) {
#pragma unroll
    for (int i = 0; i < 4; ++i) {
      int idx = tid + i * 256;
      int mm = idx >> 4, kk = idx & 15;
      int gm = m0 + mm, gk = k0 + kk;
      As[kk][mm] = (gm < M && gk < K) ? A[(size_t)gm * lda + gk] : 0.f;
      int gn = n0 + mm;
      Ws[kk][mm] = (gn < N && gk < K) ? W[(size_t)gn * ldw + gk] : 0.f;
    }
    __syncthreads();
#pragma unroll
    for (int kk = 0; kk < 16; ++kk) {
      float a[4], b[4];
#pragma unroll
      for (int i = 0; i < 4; ++i) a[i] = As[kk][ty * 4 + i];
#pragma unroll
      for (int j = 0; j < 4; ++j) b[j] = Ws[kk][tx * 4 + j];
#pragma unroll
      for (int i = 0; i < 4; ++i)
#pragma unroll
        for (int j = 0; j < 4; ++j) acc[i][j] = fmaf(a[i], b[j], acc[i][j]);
    }
    __syncthreads();
  }
#pragma unroll
  for (int i = 0; i < 4; ++i) {
    int gm = m0 + ty * 4 + i;
    if (gm >= M) continue;
#pragma unroll
    for (int j = 0; j < 4; ++j) {
      int gn = n0 + tx * 4 + j;
      if (gn >= N) continue;
      float v = acc[i][j];
      if (bias) v += bias[gn];
      C[(size_t)gm * ldc + gn] = v;
    }
  }
}

// ===================== weight casts =====================
__global__ __launch_bounds__(256) void cast_k(const float* __restrict__ s, ushort_t* __restrict__ d, int n)
{
  int i = blockIdx.x * 256 + threadIdx.x;
  if (i < n) d[i] = f2bf(s[i]);
}

__global__ __launch_bounds__(256) void cast_layer_k(
    const float* __restrict__ iw, const float* __restrict__ ow,
    const float* __restrict__ xw, const float* __restrict__ xwb,
    const float* __restrict__ dw, const float* __restrict__ dwb,
    ushort_t* __restrict__ wIn, ushort_t* __restrict__ wOut,
    ushort_t* __restrict__ wXF, ushort_t* __restrict__ wXB,
    ushort_t* __restrict__ wDF, ushort_t* __restrict__ wDB)
{
  int j = blockIdx.x * 256 + threadIdx.x;
  if (j < 2359296) { wIn[j] = f2bf(iw[j]); return; } j -= 2359296;
  if (j < 1179648) { wOut[j] = f2bf(ow[j]); return; } j -= 1179648;
  if (j < 196608) { int r = j / 1536, k = j - r * 1536;
    wXF[j] = f2bf(r < 80 ? xw[r * 1536 + k] : 0.f); return; } j -= 196608;
  if (j < 196608) { int r = j / 1536, k = j - r * 1536;
    wXB[j] = f2bf(r < 80 ? xwb[r * 1536 + k] : 0.f); return; } j -= 196608;
  if (j < 98304) { int d = j >> 6, k = j & 63;
    wDF[j] = f2bf(k < 48 ? dw[d * 48 + k] : 0.f); return; } j -= 98304;
  if (j < 98304) { int d = j >> 6, k = j & 63;
    wDB[j] = f2bf(k < 48 ? dwb[d * 48 + k] : 0.f); }
}

// ===================== im2col =====================
__global__ __launch_bounds__(256) void im2col_v(const float* __restrict__ xv, ushort_t* __restrict__ Av)
{
  int i = blockIdx.x * 256 + threadIdx.x;
  if (i >= 1568 * 768) return;
  int m = i / 768, k = i % 768;
  int c = k >> 8, r = k & 255;
  int kh = r >> 4, kw = r & 15;
  int bt = m / 196, n = m % 196;
  int b = bt / TT, t = bt % TT;
  int hb = n / 14, wb = n % 14;
  Av[i] = f2bf(xv[(size_t)b * 602112 + (size_t)c * 200704 + t * 50176 + (hb * 16 + kh) * 224 + wb * 16 + kw]);
}

__global__ __launch_bounds__(256) void im2col_a(const float* __restrict__ xa, float* __restrict__ Aa)
{
  int i = blockIdx.x * 256 + threadIdx.x;
  if (i >= 192 * 256) return;
  int m = i / 256, k = i % 256;
  int kh = k >> 4, kw = k & 15;
  int b = m / 96, q = m % 96;
  int tb = q >> 2, fb = q & 3;
  Aa[i] = xa[(size_t)b * 24576 + (fb * 16 + kw) * 384 + tb * 16 + kh];
}

// ===================== assemble tokens + gather =====================
__global__ __launch_bounds__(256) void assemble_k(
    const float* __restrict__ tokv, const float* __restrict__ toka,
    const float* __restrict__ pos_v, const float* __restrict__ pos_a,
    const float* __restrict__ tpos_v, const float* __restrict__ tpos_a,
    const float* __restrict__ cls_v, const float* __restrict__ cls_a,
    const float* __restrict__ glob_v, const float* __restrict__ glob_a,
    const int* __restrict__ vis_idx,
    float* __restrict__ h, float* __restrict__ res)
{
  int i = blockIdx.x * 256 + threadIdx.x;
  if (i >= NROWS * DD) return;
  int d = i % DD;
  int bl = i / DD;
  int r = bl % LV, b = bl / LV;
  int tok = vis_idx[b * LV + r];
  int t = tok / 224, q = tok % 224;
  float v;
  if (q == 0) v = cls_v[d];
  else if (q <= 196) {
    int n = q - 1;
    v = tokv[((size_t)(b * TT + t) * 196 + n) * DD + d] + pos_v[n * DD + d] + tpos_v[t * DD + d];
  } else if (q == 197) v = glob_v[d];
  else if (q == 198) v = cls_a[d];
  else if (q <= 222) {
    int n = q - 199;
    v = toka[((size_t)b * 96 + t * 24 + n) * DD + d] + pos_a[n * DD + d] + tpos_a[t * DD + d];
  } else v = glob_a[d];
  h[i] = v;
  res[i] = 0.f;
}

// ===================== fused residual add + RMSNorm (bf16 out) =====================
__global__ __launch_bounds__(256) void rmsnorm_k(
    const float* __restrict__ h, float* __restrict__ res,
    ushort_t* __restrict__ hn, const float* __restrict__ nw)
{
  int row = blockIdx.x;
  const float* hp = h + (size_t)row * DD;
  float* rp = res + (size_t)row * DD;
  ushort_t* op = hn + (size_t)row * DD;
  int tid = threadIdx.x;
  float v[3];
  float ss = 0.f;
#pragma unroll
  for (int i = 0; i < 3; ++i) {
    float x = hp[tid + i * 256] + rp[tid + i * 256];
    v[i] = x;
    ss += x * x;
  }
  for (int m = 1; m < 64; m <<= 1) ss += __shfl_xor(ss, m, 64);
  __shared__ float sred[4];
  if ((tid & 63) == 0) sred[tid >> 6] = ss;
  __syncthreads();
  float tot = sred[0] + sred[1] + sred[2] + sred[3];
  float sc = rsqrtf(tot / (float)DD + 1e-5f);
#pragma unroll
  for (int i = 0; i < 3; ++i) {
    int c = tid + i * 256;
    rp[c] = v[i];
    op[c] = f2bf(v[i] * sc * nw[c]);
  }
}

// ===================== causal depthwise conv (k=4) + silu, fwd + rev =============
__global__ __launch_bounds__(256) void conv_k(
    const float* __restrict__ xz,
    const float* __restrict__ cw, const float* __restrict__ cb,
    const float* __restrict__ cwb, const float* __restrict__ cbb,
    float* __restrict__ xcF, float* __restrict__ xcB,
    ushort_t* __restrict__ xcFb, ushort_t* __restrict__ xcBb)
{
  int i = blockIdx.x * 256 + threadIdx.x;
  if (i >= NROWS * DI_) return;
  int d = i % DI_;
  int bl = i / DI_;
  int l = bl % LV, b = bl / LV;
  const float* xzb = xz + (size_t)b * LV * (2 * DI_);
  float accf = cb[d];
#pragma unroll
  for (int j = 0; j < 4; ++j) {
    int lp = l - 3 + j;
    if (lp >= 0) accf += xzb[(size_t)lp * (2 * DI_) + d] * cw[d * 4 + j];
  }
  float accb = cbb[d];
#pragma unroll
  for (int j = 0; j < 4; ++j) {
    int lp = l - 3 + j;
    if (lp >= 0) accb += xzb[(size_t)(LV - 1 - lp) * (2 * DI_) + d] * cwb[d * 4 + j];
  }
  float sf = silu_f(accf), sb = silu_f(accb);
  xcF[i] = sf; xcB[i] = sb;
  xcFb[i] = f2bf(sf); xcBb[i] = f2bf(sb);
}

// ===================== split-K reduce + dtr bf16 pack (pad 48->64) ==============
__global__ __launch_bounds__(256) void reduce_pack_k(
    const float* __restrict__ pF, const float* __restrict__ pB,
    float* __restrict__ prF, float* __restrict__ prB,
    ushort_t* __restrict__ dF, ushort_t* __restrict__ dB)
{
  int i = blockIdx.x * 256 + threadIdx.x;   // over 896*128
  if (i >= NROWS * 128) return;
  int dir = blockIdx.y;
  const float* part = dir ? pB : pF;
  float* proj = dir ? prB : prF;
  ushort_t* dtr = dir ? dB : dF;
  int row = i >> 7, col = i & 127;
  float s = 0.f;
  if (col < 80) {
#pragma unroll
    for (int c = 0; c < 4; ++c) s += part[c * (NROWS * 128) + i];
    proj[row * 80 + col] = s;
  }
  if (col < 64) dtr[(row << 6) + col] = f2bf(col < 48 ? s : 0.f);
}

// ===================== selective scan =====================
__global__ __launch_bounds__(256) void scan_k(
    const float* __restrict__ xcF, const float* __restrict__ dtF, const float* __restrict__ prF,
    const float* __restrict__ xcB, const float* __restrict__ dtB, const float* __restrict__ prB,
    const float* __restrict__ AlF, const float* __restrict__ AlB,
    const float* __restrict__ DpF, const float* __restrict__ DpB,
    float* __restrict__ yF, float* __restrict__ yB)
{
  int dir = blockIdx.y;
  const float* xc = dir ? xcB : xcF;
  const float* dt = dir ? dtB : dtF;
  const float* pr = dir ? prB : prF;
  const float* Al = dir ? AlB : AlF;
  const float* Dpp = dir ? DpB : DpF;
  float* y = dir ? yB : yF;

  int g = blockIdx.x * 16 + (threadIdx.x >> 4);
  int n = threadIdx.x & 15;
  int b = g / DI_, d = g % DI_;
  float An = -__expf(Al[d * NS_ + n]);
  float Dpd = Dpp[d];
  float hs = 0.f;
  const float* xcp = xc + (size_t)b * LV * DI_ + d;
  const float* dtp = dt + (size_t)b * LV * DI_ + d;
  const float* prp = pr + (size_t)b * LV * 80;
  float* yp = y + (size_t)b * LV * DI_ + d;

  float dtv = dtp[0];
  float xcv = xcp[0];
  float bn = prp[48 + n];
  float cn = prp[64 + n];
  for (int l = 0; l < LV; ++l) {
    float dtv_n = 0.f, xcv_n = 0.f, bn_n = 0.f, cn_n = 0.f;
    if (l + 1 < LV) {
      dtv_n = dtp[(size_t)(l + 1) * DI_];
      xcv_n = xcp[(size_t)(l + 1) * DI_];
      bn_n = prp[(l + 1) * 80 + 48 + n];
      cn_n = prp[(l + 1) * 80 + 64 + n];
    }
    hs = __expf(dtv * An) * hs + dtv * bn * xcv;
    float p = hs * cn;
    p += __shfl_xor(p, 1, 16);
    p += __shfl_xor(p, 2, 16);
    p += __shfl_xor(p, 4, 16);
    p += __shfl_xor(p, 8, 16);
    if (n == 0) yp[(size_t)l * DI_] = p + xcv * Dpd;
    dtv = dtv_n; xcv = xcv_n; bn = bn_n; cn = cn_n;
  }
}

// ===================== combine (bf16 out) =====================
__global__ __launch_bounds__(256) void combine_k(
    const float* __restrict__ yF, const float* __restrict__ yB,
    const float* __restrict__ xz, ushort_t* __restrict__ yc)
{
  int i = blockIdx.x * 256 + threadIdx.x;
  if (i >= NROWS * DI_) return;
  int d = i % DI_;
  int bl = i / DI_;
  int l = bl % LV, b = bl / LV;
  float z = xz[(size_t)(b * LV + l) * (2 * DI_) + DI_ + d];
  float v = (yF[i] + yB[((size_t)b * LV + (LV - 1 - l)) * DI_ + d]) * silu_f(z);
  yc[i] = f2bf(v);
}

__global__ __launch_bounds__(256) void copy_k(const float* __restrict__ src, float* __restrict__ dst, int n)
{
  int i = blockIdx.x * 256 + threadIdx.x;
  if (i < n) dst[i] = src[i];
}

extern "C" void kernel_launch(void* const* d_in, const int* in_sizes, int n_in,
                              void* d_out, int out_size, void* d_ws, size_t ws_size,
                              hipStream_t stream)
{
  const float* x_v = (const float*)d_in[0];
  const float* x_a = (const float*)d_in[1];
  const float* patch_v_w = (const float*)d_in[2];
  const float* patch_v_b = (const float*)d_in[3];
  const float* patch_a_w = (const float*)d_in[4];
  const float* patch_a_b = (const float*)d_in[5];
  const float* pos_v = (const float*)d_in[6];
  const float* pos_a = (const float*)d_in[7];
  const float* tpos_v = (const float*)d_in[8];
  const float* tpos_a = (const float*)d_in[9];
  const float* cls_v = (const float*)d_in[10];
  const float* cls_a = (const float*)d_in[11];
  const float* glob_v = (const float*)d_in[12];
  const float* glob_a = (const float*)d_in[13];
  const float* norm_w = (const float*)d_in[14];
  const float* in_w = (const float*)d_in[15];
  const float* conv_w = (const float*)d_in[16];
  const float* conv_b = (const float*)d_in[17];
  const float* conv_w_b = (const float*)d_in[18];
  const float* conv_b_b = (const float*)d_in[19];
  const float* xproj_w = (const float*)d_in[20];
  const float* xproj_w_b = (const float*)d_in[21];
  const float *dt_w, *dt_bias, *dt_w_b, *dt_bias_b;
  if (in_sizes[23] == DEPTH_ * DI_ * RK_) {  // dict order: dt_w, dt_w_b, dt_b, dt_b_b
    dt_w = (const float*)d_in[22]; dt_w_b = (const float*)d_in[23];
    dt_bias = (const float*)d_in[24]; dt_bias_b = (const float*)d_in[25];
  } else {                                   // signature order
    dt_w = (const float*)d_in[22]; dt_bias = (const float*)d_in[23];
    dt_w_b = (const float*)d_in[24]; dt_bias_b = (const float*)d_in[25];
  }
  const float* A_log = (const float*)d_in[26];
  const float* A_log_b = (const float*)d_in[27];
  const float* D_par = (const float*)d_in[28];
  const float* D_par_b = (const float*)d_in[29];
  const float* out_w = (const float*)d_in[30];
  const int* vis_idx = (const int*)d_in[31];

  // ---------------- workspace layout (floats), lifetime-aliased: 61.1 MB ----------
  float* ws = (float*)d_ws;
  float* res   = ws;                 // 688128
  float* hbuf  = ws + 688128;        // 688128
  float* R1    = ws + 1376256;       // 2752512: partF+partB (xproj) | yF+yB (scan)
  float* R2f   = ws + 4128768;       // 688128:  hn_bf | dtr pads | ycb (ushort region)
  float* R3    = ws + 4816896;       // 2752512: xcFb+xcBb (ushort) | dtF+dtB (f32)
  float* xz    = ws + 7569408;       // 2752512
  float* xcF   = ws + 10321920;      // 1376256
  float* xcB   = ws + 11698176;      // 1376256
  float* projF = ws + 13074432;      // 71680
  float* projB = ws + 13146112;      // 71680
  float* wreg  = ws + 13217792;      // 2064384 f of bf16 weights

  // R1 views
  float* partF = R1;                         // 4*896*128
  float* partB = R1 + 458752;
  float* yF    = R1;                         // 896*1536
  float* yB    = R1 + 1376256;
  // phase-1 views (dead before layer loop)
  float* tokv  = R1;                         // 1568*768
  float* toka  = R1 + 1204224;               // 192*768
  float* Aa    = R1 + 1351680;               // 192*256
  ushort_t* Av_bf = (ushort_t*)xz;           // 1568*768 bf16
  ushort_t* wPv   = (ushort_t*)xcF;          // 768*768 bf16
  // R2 views (ushort)
  ushort_t* hn_bf = (ushort_t*)R2f;          // 896*768
  ushort_t* dtrF  = (ushort_t*)R2f;          // 896*64
  ushort_t* dtrB  = ((ushort_t*)R2f) + 57344;
  ushort_t* ycb   = (ushort_t*)R2f;          // 896*1536
  // R3 views
  ushort_t* xcFb = (ushort_t*)R3;            // 896*1536
  ushort_t* xcBb = ((ushort_t*)R3) + 1376256;
  float* dtF = R3;                           // 896*1536 f32
  float* dtB = R3 + 1376256;
  // weight views (ushort)
  ushort_t* wIn  = (ushort_t*)wreg;          // 3072*768
  ushort_t* wOut = wIn + 2359296;            // 768*1536
  ushort_t* wXF  = wOut + 1179648;           // 128*1536
  ushort_t* wXB  = wXF + 196608;
  ushort_t* wDF  = wXB + 196608;             // 1536*64
  ushort_t* wDB  = wDF + 98304;

  dim3 blk(256);

  // ---- phase 1: patch embed + assemble ----
  im2col_v<<<4704, blk, 0, stream>>>(x_v, Av_bf);
  cast_k<<<2304, blk, 0, stream>>>(patch_v_w, wPv, 589824);
  im2col_a<<<192, blk, 0, stream>>>(x_a, Aa);
  mfma_gemm<<<dim3(6, 13, 1), blk, 0, stream>>>(Av_bf, nullptr, 768, wPv, nullptr, 768,
                                                patch_v_b, nullptr, tokv, nullptr, 768,
                                                1568, 768, 1, 0, 0);
  gemm_nt<<<dim3(12, 3, 1), blk, 0, stream>>>(Aa, 256, patch_a_w, 256, patch_a_b,
                                              toka, 768, 192, 768, 256);
  assemble_k<<<2688, blk, 0, stream>>>(tokv, toka, pos_v, pos_a, tpos_v, tpos_a,
                                       cls_v, cls_a, glob_v, glob_a, vis_idx, hbuf, res);

  // ---- phase 2: 16 layers ----
  for (int l = 0; l < DEPTH_; ++l) {
    const float* nw  = norm_w + l * DD;
    const float* iw  = in_w + (size_t)l * 2 * DI_ * DD;
    const float* cw  = conv_w + l * DI_ * KC_;
    const float* cb  = conv_b + l * DI_;
    const float* cwb = conv_w_b + l * DI_ * KC_;
    const float* cbb = conv_b_b + l * DI_;
    const float* xw  = xproj_w + (size_t)l * 80 * DI_;
    const float* xwb = xproj_w_b + (size_t)l * 80 * DI_;
    const float* dw  = dt_w + (size_t)l * DI_ * RK_;
    const float* dbi = dt_bias + l * DI_;
    const float* dwb = dt_w_b + (size_t)l * DI_ * RK_;
    const float* dbib = dt_bias_b + l * DI_;
    const float* al  = A_log + (size_t)l * DI_ * NS_;
    const float* alb = A_log_b + (size_t)l * DI_ * NS_;
    const float* dp  = D_par + l * DI_;
    const float* dpb = D_par_b + l * DI_;
    const float* ow  = out_w + (size_t)l * DD * DI_;

    cast_layer_k<<<16128, blk, 0, stream>>>(iw, ow, xw, xwb, dw, dwb,
                                            wIn, wOut, wXF, wXB, wDF, wDB);
    rmsnorm_k<<<NROWS, blk, 0, stream>>>(hbuf, res, hn_bf, nw);
    // in-proj: [896,3072] = hn[896,768] @ in_w^T
    mfma_gemm<<<dim3(24, 7, 1), blk, 0, stream>>>(hn_bf, nullptr, 768, wIn, nullptr, 768,
                                                  nullptr, nullptr, xz, nullptr, 3072,
                                                  NROWS, 768, 1, 0, 0);
    conv_k<<<5376, blk, 0, stream>>>(xz, cw, cb, cwb, cbb, xcF, xcB, xcFb, xcBb);
    // xproj both dirs, split-K x4 (N padded to 128)
    mfma_gemm<<<dim3(1, 7, 8), blk, 0, stream>>>(xcFb, xcBb, 1536, wXF, wXB, 1536,
                                                 nullptr, nullptr, partF, partB, 128,
                                                 NROWS, 1536, 4, NROWS * 128, 0);
    reduce_pack_k<<<dim3(448, 2, 1), blk, 0, stream>>>(partF, partB, projF, projB, dtrF, dtrB);
    // dt both dirs: [896,1536] = dtr[896,64] @ dtw_pad^T, softplus+bias fused
    mfma_gemm<<<dim3(12, 7, 2), blk, 0, stream>>>(dtrF, dtrB, 64, wDF, wDB, 64,
                                                  dbi, dbib, dtF, dtB, 1536,
                                                  NROWS, 64, 1, 0, 1);
    scan_k<<<dim3(192, 2, 1), blk, 0, stream>>>(xcF, dtF, projF, xcB, dtB, projB,
                                                al, alb, dp, dpb, yF, yB);
    combine_k<<<5376, blk, 0, stream>>>(yF, yB, xz, ycb);
    // out-proj: [896,768] = yc[896,1536] @ out_w^T
    mfma_gemm<<<dim3(6, 7, 1), blk, 0, stream>>>(ycb, nullptr, 1536, wOut, nullptr, 1536,
                                                 nullptr, nullptr, hbuf, nullptr, 768,
                                                 NROWS, 1536, 1, 0, 0);
  }

  copy_k<<<2688, blk, 0, stream>>>(res, (float*)d_out, out_size);
}

// Round 3
// 3826.701 us; speedup vs baseline: 2.6814x; 1.3193x over previous
//
#include <hip/hip_runtime.h>
#include <math.h>

typedef unsigned short ushort_t;
typedef __attribute__((ext_vector_type(8))) short bf16x8;
typedef __attribute__((ext_vector_type(4))) float f32x4;

#define NBATCH 2
#define TT 4
#define DD 768
#define DI_ 1536
#define NS_ 16
#define RK_ 48
#define KC_ 4
#define DEPTH_ 16
#define LV 448
#define NROWS (NBATCH*LV)   // 896
#define NCH 7               // scan chunks
#define CLEN 64             // chunk length (7*64 = 448)

__device__ __forceinline__ float silu_f(float x) { return x / (1.f + __expf(-x)); }
__device__ __forceinline__ ushort_t f2bf(float x) {
  unsigned int u = __float_as_uint(x);
  return (ushort_t)((u + 0x7FFFu + ((u >> 16) & 1u)) >> 16);
}

typedef const __attribute__((address_space(1))) unsigned int* gas1_t;
typedef __attribute__((address_space(3))) unsigned int* las3_t;
__device__ __forceinline__ void gll16(const ushort_t* g, ushort_t* l) {
  __builtin_amdgcn_global_load_lds((gas1_t)g, (las3_t)l, 16, 0, 0);
}

// ===================== bf16 MFMA GEMM: C[M,N] = A[M,K] @ W[N,K]^T ==============
__global__ __launch_bounds__(256) void mfma_gemm(
    const ushort_t* __restrict__ A, const ushort_t* __restrict__ A2, int lda,
    const ushort_t* __restrict__ W, const ushort_t* __restrict__ W2, int ldw,
    const float* __restrict__ bias, const float* __restrict__ bias2,
    float* __restrict__ C, float* __restrict__ C2, int ldc,
    int M, int K, int nkChunks, long partStride, int epi)
{
  int z = blockIdx.z;
  int dir = z / nkChunks, chunk = z - dir * nkChunks;
  if (dir) { A = A2; W = W2; C = C2; bias = bias2; }
  int kChunk = K / nkChunks;
  int kbeg = chunk * kChunk;
  if (nkChunks > 1) C += (long)chunk * partStride;

  __shared__ __align__(16) ushort_t At[128 * 32];
  __shared__ __align__(16) ushort_t Bt[128 * 32];

  int tid = threadIdx.x, wv = tid >> 6, lane = tid & 63;
  int m0 = blockIdx.y * 128, n0 = blockIdx.x * 128;

  int S0 = wv * 128 + lane, S1 = S0 + 64;
  int r0 = S0 >> 2, g0 = (S0 & 3) ^ ((r0 >> 1) & 3);
  int r1 = S1 >> 2, g1 = (S1 & 3) ^ ((r1 >> 1) & 3);
  const ushort_t* a0 = A + (size_t)min(m0 + r0, M - 1) * lda + g0 * 8 + kbeg;
  const ushort_t* a1 = A + (size_t)min(m0 + r1, M - 1) * lda + g1 * 8 + kbeg;
  const ushort_t* b0 = W + (size_t)(n0 + r0) * ldw + g0 * 8 + kbeg;
  const ushort_t* b1 = W + (size_t)(n0 + r1) * ldw + g1 * 8 + kbeg;
  ushort_t* lA0 = At + S0 * 8; ushort_t* lA1 = At + S1 * 8;
  ushort_t* lB0 = Bt + S0 * 8; ushort_t* lB1 = Bt + S1 * 8;

  int wr = wv >> 1, wc = wv & 1;
  int rl = lane & 15, gl = lane >> 4;
  int offA[4], offB[4];
#pragma unroll
  for (int i = 0; i < 4; ++i) {
    int ra = wr * 64 + i * 16 + rl;
    offA[i] = ra * 32 + ((gl ^ ((ra >> 1) & 3)) * 8);
    int rb = wc * 64 + i * 16 + rl;
    offB[i] = rb * 32 + ((gl ^ ((rb >> 1) & 3)) * 8);
  }

  f32x4 acc[4][4] = {};
  int nk = kChunk >> 5;
  for (int t = 0; t < nk; ++t) {
    int ko = t << 5;
    gll16(a0 + ko, lA0); gll16(a1 + ko, lA1);
    gll16(b0 + ko, lB0); gll16(b1 + ko, lB1);
    __syncthreads();
    bf16x8 af[4], bw[4];
#pragma unroll
    for (int i = 0; i < 4; ++i) {
      af[i] = *(const bf16x8*)(At + offA[i]);
      bw[i] = *(const bf16x8*)(Bt + offB[i]);
    }
#pragma unroll
    for (int i = 0; i < 4; ++i)
#pragma unroll
      for (int j = 0; j < 4; ++j)
        acc[i][j] = __builtin_amdgcn_mfma_f32_16x16x32_bf16(af[i], bw[j], acc[i][j], 0, 0, 0);
    __syncthreads();
  }

#pragma unroll
  for (int i = 0; i < 4; ++i) {
    int row0 = m0 + wr * 64 + i * 16 + gl * 4;
#pragma unroll
    for (int q = 0; q < 4; ++q) {
      int row = row0 + q;
      if (row >= M) continue;
#pragma unroll
      for (int j = 0; j < 4; ++j) {
        int col = n0 + wc * 64 + j * 16 + rl;
        float v = acc[i][j][q];
        if (bias) v += bias[col];
        if (epi == 1) v = (v > 20.f) ? v : log1pf(__expf(v));
        C[(size_t)row * ldc + col] = v;
      }
    }
  }
}

// ===================== fp32 GEMM (audio patch only) =====================
__global__ __launch_bounds__(256) void gemm_nt(
    const float* __restrict__ A, int lda,
    const float* __restrict__ W, int ldw,
    const float* __restrict__ bias,
    float* __restrict__ C, int ldc, int M, int N, int K)
{
  __shared__ float As[16][68];
  __shared__ float Ws[16][68];
  int tid = threadIdx.x;
  int m0 = blockIdx.y * 64, n0 = blockIdx.x * 64;
  int ty = tid >> 4, tx = tid & 15;
  float acc[4][4] = {};
  for (int k0 = 0; k0 < K; k0 += 16) {
#pragma unroll
    for (int i = 0; i < 4; ++i) {
      int idx = tid + i * 256;
      int mm = idx >> 4, kk = idx & 15;
      int gm = m0 + mm, gk = k0 + kk;
      As[kk][mm] = (gm < M && gk < K) ? A[(size_t)gm * lda + gk] : 0.f;
      int gn = n0 + mm;
      Ws[kk][mm] = (gn < N && gk < K) ? W[(size_t)gn * ldw + gk] : 0.f;
    }
    __syncthreads();
#pragma unroll
    for (int kk = 0; kk < 16; ++kk) {
      float a[4], b[4];
#pragma unroll
      for (int i = 0; i < 4; ++i) a[i] = As[kk][ty * 4 + i];
#pragma unroll
      for (int j = 0; j < 4; ++j) b[j] = Ws[kk][tx * 4 + j];
#pragma unroll
      for (int i = 0; i < 4; ++i)
#pragma unroll
        for (int j = 0; j < 4; ++j) acc[i][j] = fmaf(a[i], b[j], acc[i][j]);
    }
    __syncthreads();
  }
#pragma unroll
  for (int i = 0; i < 4; ++i) {
    int gm = m0 + ty * 4 + i;
    if (gm >= M) continue;
#pragma unroll
    for (int j = 0; j < 4; ++j) {
      int gn = n0 + tx * 4 + j;
      if (gn >= N) continue;
      float v = acc[i][j];
      if (bias) v += bias[gn];
      C[(size_t)gm * ldc + gn] = v;
    }
  }
}

// ===================== weight casts =====================
__global__ __launch_bounds__(256) void cast_k(const float* __restrict__ s, ushort_t* __restrict__ d, int n)
{
  int i = blockIdx.x * 256 + threadIdx.x;
  if (i < n) d[i] = f2bf(s[i]);
}

__global__ __launch_bounds__(256) void cast_layer_k(
    const float* __restrict__ iw, const float* __restrict__ ow,
    const float* __restrict__ xw, const float* __restrict__ xwb,
    const float* __restrict__ dw, const float* __restrict__ dwb,
    ushort_t* __restrict__ wIn, ushort_t* __restrict__ wOut,
    ushort_t* __restrict__ wXF, ushort_t* __restrict__ wXB,
    ushort_t* __restrict__ wDF, ushort_t* __restrict__ wDB)
{
  int j = blockIdx.x * 256 + threadIdx.x;
  if (j < 2359296) { wIn[j] = f2bf(iw[j]); return; } j -= 2359296;
  if (j < 1179648) { wOut[j] = f2bf(ow[j]); return; } j -= 1179648;
  if (j < 196608) { int r = j / 1536, k = j - r * 1536;
    wXF[j] = f2bf(r < 80 ? xw[r * 1536 + k] : 0.f); return; } j -= 196608;
  if (j < 196608) { int r = j / 1536, k = j - r * 1536;
    wXB[j] = f2bf(r < 80 ? xwb[r * 1536 + k] : 0.f); return; } j -= 196608;
  if (j < 98304) { int d = j >> 6, k = j & 63;
    wDF[j] = f2bf(k < 48 ? dw[d * 48 + k] : 0.f); return; } j -= 98304;
  if (j < 98304) { int d = j >> 6, k = j & 63;
    wDB[j] = f2bf(k < 48 ? dwb[d * 48 + k] : 0.f); }
}

// ===================== im2col =====================
__global__ __launch_bounds__(256) void im2col_v(const float* __restrict__ xv, ushort_t* __restrict__ Av)
{
  int i = blockIdx.x * 256 + threadIdx.x;
  if (i >= 1568 * 768) return;
  int m = i / 768, k = i % 768;
  int c = k >> 8, r = k & 255;
  int kh = r >> 4, kw = r & 15;
  int bt = m / 196, n = m % 196;
  int b = bt / TT, t = bt % TT;
  int hb = n / 14, wb = n % 14;
  Av[i] = f2bf(xv[(size_t)b * 602112 + (size_t)c * 200704 + t * 50176 + (hb * 16 + kh) * 224 + wb * 16 + kw]);
}

__global__ __launch_bounds__(256) void im2col_a(const float* __restrict__ xa, float* __restrict__ Aa)
{
  int i = blockIdx.x * 256 + threadIdx.x;
  if (i >= 192 * 256) return;
  int m = i / 256, k = i % 256;
  int kh = k >> 4, kw = k & 15;
  int b = m / 96, q = m % 96;
  int tb = q >> 2, fb = q & 3;
  Aa[i] = xa[(size_t)b * 24576 + (fb * 16 + kw) * 384 + tb * 16 + kh];
}

// ===================== assemble tokens + gather =====================
__global__ __launch_bounds__(256) void assemble_k(
    const float* __restrict__ tokv, const float* __restrict__ toka,
    const float* __restrict__ pos_v, const float* __restrict__ pos_a,
    const float* __restrict__ tpos_v, const float* __restrict__ tpos_a,
    const float* __restrict__ cls_v, const float* __restrict__ cls_a,
    const float* __restrict__ glob_v, const float* __restrict__ glob_a,
    const int* __restrict__ vis_idx,
    float* __restrict__ h, float* __restrict__ res)
{
  int i = blockIdx.x * 256 + threadIdx.x;
  if (i >= NROWS * DD) return;
  int d = i % DD;
  int bl = i / DD;
  int r = bl % LV, b = bl / LV;
  int tok = vis_idx[b * LV + r];
  int t = tok / 224, q = tok % 224;
  float v;
  if (q == 0) v = cls_v[d];
  else if (q <= 196) {
    int n = q - 1;
    v = tokv[((size_t)(b * TT + t) * 196 + n) * DD + d] + pos_v[n * DD + d] + tpos_v[t * DD + d];
  } else if (q == 197) v = glob_v[d];
  else if (q == 198) v = cls_a[d];
  else if (q <= 222) {
    int n = q - 199;
    v = toka[((size_t)b * 96 + t * 24 + n) * DD + d] + pos_a[n * DD + d] + tpos_a[t * DD + d];
  } else v = glob_a[d];
  h[i] = v;
  res[i] = 0.f;
}

// ===================== fused residual add + RMSNorm (bf16 out) =====================
__global__ __launch_bounds__(256) void rmsnorm_k(
    const float* __restrict__ h, float* __restrict__ res,
    ushort_t* __restrict__ hn, const float* __restrict__ nw)
{
  int row = blockIdx.x;
  const float* hp = h + (size_t)row * DD;
  float* rp = res + (size_t)row * DD;
  ushort_t* op = hn + (size_t)row * DD;
  int tid = threadIdx.x;
  float v[3];
  float ss = 0.f;
#pragma unroll
  for (int i = 0; i < 3; ++i) {
    float x = hp[tid + i * 256] + rp[tid + i * 256];
    v[i] = x;
    ss += x * x;
  }
  for (int m = 1; m < 64; m <<= 1) ss += __shfl_xor(ss, m, 64);
  __shared__ float sred[4];
  if ((tid & 63) == 0) sred[tid >> 6] = ss;
  __syncthreads();
  float tot = sred[0] + sred[1] + sred[2] + sred[3];
  float sc = rsqrtf(tot / (float)DD + 1e-5f);
#pragma unroll
  for (int i = 0; i < 3; ++i) {
    int c = tid + i * 256;
    rp[c] = v[i];
    op[c] = f2bf(v[i] * sc * nw[c]);
  }
}

// ===================== causal depthwise conv (k=4) + silu, fwd + rev =============
__global__ __launch_bounds__(256) void conv_k(
    const float* __restrict__ xz,
    const float* __restrict__ cw, const float* __restrict__ cb,
    const float* __restrict__ cwb, const float* __restrict__ cbb,
    float* __restrict__ xcF, float* __restrict__ xcB,
    ushort_t* __restrict__ xcFb, ushort_t* __restrict__ xcBb)
{
  int i = blockIdx.x * 256 + threadIdx.x;
  if (i >= NROWS * DI_) return;
  int d = i % DI_;
  int bl = i / DI_;
  int l = bl % LV, b = bl / LV;
  const float* xzb = xz + (size_t)b * LV * (2 * DI_);
  float accf = cb[d];
#pragma unroll
  for (int j = 0; j < 4; ++j) {
    int lp = l - 3 + j;
    if (lp >= 0) accf += xzb[(size_t)lp * (2 * DI_) + d] * cw[d * 4 + j];
  }
  float accb = cbb[d];
#pragma unroll
  for (int j = 0; j < 4; ++j) {
    int lp = l - 3 + j;
    if (lp >= 0) accb += xzb[(size_t)(LV - 1 - lp) * (2 * DI_) + d] * cwb[d * 4 + j];
  }
  float sf = silu_f(accf), sb = silu_f(accb);
  xcF[i] = sf; xcB[i] = sb;
  xcFb[i] = f2bf(sf); xcBb[i] = f2bf(sb);
}

// ===================== split-K reduce + dtr bf16 pack (pad 48->64) ==============
__global__ __launch_bounds__(256) void reduce_pack_k(
    const float* __restrict__ pF, const float* __restrict__ pB,
    float* __restrict__ prF, float* __restrict__ prB,
    ushort_t* __restrict__ dF, ushort_t* __restrict__ dB)
{
  int i = blockIdx.x * 256 + threadIdx.x;   // over 896*128
  if (i >= NROWS * 128) return;
  int dir = blockIdx.y;
  const float* part = dir ? pB : pF;
  float* proj = dir ? prB : prF;
  ushort_t* dtr = dir ? dB : dF;
  int row = i >> 7, col = i & 127;
  float s = 0.f;
  if (col < 80) {
#pragma unroll
    for (int c = 0; c < 4; ++c) s += part[c * (NROWS * 128) + i];
    proj[row * 80 + col] = s;
  }
  if (col < 64) dtr[(row << 6) + col] = f2bf(col < 48 ? s : 0.f);
}

// ===================== chunked selective scan =====================
// pass A: chunks 0..5 compute local final state (h from 0) and P = exp(An * sum dt)
__global__ __launch_bounds__(256) void scanA_k(
    const float* __restrict__ xcF, const float* __restrict__ dtF, const float* __restrict__ prF,
    const float* __restrict__ xcB, const float* __restrict__ dtB, const float* __restrict__ prB,
    const float* __restrict__ AlF, const float* __restrict__ AlB,
    float* __restrict__ hloc, float* __restrict__ Pb)
{
  int dir = blockIdx.z;
  const float* xc = dir ? xcB : xcF;
  const float* dt = dir ? dtB : dtF;
  const float* pr = dir ? prB : prF;
  const float* Al = dir ? AlB : AlF;
  int c = blockIdx.y;
  int g = blockIdx.x * 16 + (threadIdx.x >> 4);
  int n = threadIdx.x & 15;
  int b = g / DI_, d = g % DI_;
  float An = -__expf(Al[d * NS_ + n]);
  const float* xcp = xc + (size_t)b * LV * DI_ + d;
  const float* dtp = dt + (size_t)b * LV * DI_ + d;
  const float* prp = pr + (size_t)b * LV * 80;
  int l0 = c * CLEN;
  float hs = 0.f, S = 0.f;
  float dtv = dtp[(size_t)l0 * DI_];
  float xcv = xcp[(size_t)l0 * DI_];
  float bn  = prp[l0 * 80 + 48 + n];
  for (int kk = 0; kk < CLEN; ++kk) {
    float dtv_n = 0.f, xcv_n = 0.f, bn_n = 0.f;
    if (kk < CLEN - 1) {
      int l1 = l0 + kk + 1;
      dtv_n = dtp[(size_t)l1 * DI_];
      xcv_n = xcp[(size_t)l1 * DI_];
      bn_n  = prp[l1 * 80 + 48 + n];
    }
    hs = __expf(dtv * An) * hs + dtv * bn * xcv;
    S += dtv;
    dtv = dtv_n; xcv = xcv_n; bn = bn_n;
  }
  int idx = ((dir * 3072 + g) * NCH + c) * NS_ + n;
  hloc[idx] = hs;
  Pb[idx] = __expf(An * S);
}

// pass "hstart": sequential over 7 chunks per (channel, n); h_start -> xz x-stripes
__global__ __launch_bounds__(256) void hstart_k(
    const float* __restrict__ hloc, const float* __restrict__ Pb, float* __restrict__ xzs)
{
  int i = blockIdx.x * 256 + threadIdx.x;   // 98304 = 6144 ch * 16 n
  int ch = i >> 4, n = i & 15;
  float h = 0.f;
#pragma unroll
  for (int c = 0; c < NCH; ++c) {
    int idx = (ch * NCH + c) * NS_ + n;
    xzs[(idx / 1536) * 3072 + (idx % 1536)] = h;
    if (c < NCH - 1) h = Pb[idx] * h + hloc[idx];
  }
}

// pass B: all 7 chunks, start from h_start, emit y
__global__ __launch_bounds__(256) void scanB_k(
    const float* __restrict__ xcF, const float* __restrict__ dtF, const float* __restrict__ prF,
    const float* __restrict__ xcB, const float* __restrict__ dtB, const float* __restrict__ prB,
    const float* __restrict__ AlF, const float* __restrict__ AlB,
    const float* __restrict__ DpF, const float* __restrict__ DpB,
    const float* __restrict__ xzs,
    float* __restrict__ yF, float* __restrict__ yB)
{
  int dir = blockIdx.z;
  const float* xc = dir ? xcB : xcF;
  const float* dt = dir ? dtB : dtF;
  const float* pr = dir ? prB : prF;
  const float* Al = dir ? AlB : AlF;
  const float* Dpp = dir ? DpB : DpF;
  float* y = dir ? yB : yF;
  int c = blockIdx.y;
  int g = blockIdx.x * 16 + (threadIdx.x >> 4);
  int n = threadIdx.x & 15;
  int b = g / DI_, d = g % DI_;
  float An = -__expf(Al[d * NS_ + n]);
  float Dpd = Dpp[d];
  const float* xcp = xc + (size_t)b * LV * DI_ + d;
  const float* dtp = dt + (size_t)b * LV * DI_ + d;
  const float* prp = pr + (size_t)b * LV * 80;
  float* yp = y + (size_t)b * LV * DI_ + d;

  int idx = ((dir * 3072 + g) * NCH + c) * NS_ + n;
  float hs = xzs[(idx / 1536) * 3072 + (idx % 1536)];
  int l0 = c * CLEN;
  float dtv = dtp[(size_t)l0 * DI_];
  float xcv = xcp[(size_t)l0 * DI_];
  float bn  = prp[l0 * 80 + 48 + n];
  float cn  = prp[l0 * 80 + 64 + n];
  for (int kk = 0; kk < CLEN; ++kk) {
    int l = l0 + kk;
    float dtv_n = 0.f, xcv_n = 0.f, bn_n = 0.f, cn_n = 0.f;
    if (kk < CLEN - 1) {
      int l1 = l + 1;
      dtv_n = dtp[(size_t)l1 * DI_];
      xcv_n = xcp[(size_t)l1 * DI_];
      bn_n  = prp[l1 * 80 + 48 + n];
      cn_n  = prp[l1 * 80 + 64 + n];
    }
    hs = __expf(dtv * An) * hs + dtv * bn * xcv;
    float p = hs * cn;
    p += __shfl_xor(p, 1, 16);
    p += __shfl_xor(p, 2, 16);
    p += __shfl_xor(p, 4, 16);
    p += __shfl_xor(p, 8, 16);
    if (n == 0) yp[(size_t)l * DI_] = p + xcv * Dpd;
    dtv = dtv_n; xcv = xcv_n; bn = bn_n; cn = cn_n;
  }
}

// ===================== combine (bf16 out) =====================
__global__ __launch_bounds__(256) void combine_k(
    const float* __restrict__ yF, const float* __restrict__ yB,
    const float* __restrict__ xz, ushort_t* __restrict__ yc)
{
  int i = blockIdx.x * 256 + threadIdx.x;
  if (i >= NROWS * DI_) return;
  int d = i % DI_;
  int bl = i / DI_;
  int l = bl % LV, b = bl / LV;
  float z = xz[(size_t)(b * LV + l) * (2 * DI_) + DI_ + d];
  float v = (yF[i] + yB[((size_t)b * LV + (LV - 1 - l)) * DI_ + d]) * silu_f(z);
  yc[i] = f2bf(v);
}

__global__ __launch_bounds__(256) void copy_k(const float* __restrict__ src, float* __restrict__ dst, int n)
{
  int i = blockIdx.x * 256 + threadIdx.x;
  if (i < n) dst[i] = src[i];
}

extern "C" void kernel_launch(void* const* d_in, const int* in_sizes, int n_in,
                              void* d_out, int out_size, void* d_ws, size_t ws_size,
                              hipStream_t stream)
{
  const float* x_v = (const float*)d_in[0];
  const float* x_a = (const float*)d_in[1];
  const float* patch_v_w = (const float*)d_in[2];
  const float* patch_v_b = (const float*)d_in[3];
  const float* patch_a_w = (const float*)d_in[4];
  const float* patch_a_b = (const float*)d_in[5];
  const float* pos_v = (const float*)d_in[6];
  const float* pos_a = (const float*)d_in[7];
  const float* tpos_v = (const float*)d_in[8];
  const float* tpos_a = (const float*)d_in[9];
  const float* cls_v = (const float*)d_in[10];
  const float* cls_a = (const float*)d_in[11];
  const float* glob_v = (const float*)d_in[12];
  const float* glob_a = (const float*)d_in[13];
  const float* norm_w = (const float*)d_in[14];
  const float* in_w = (const float*)d_in[15];
  const float* conv_w = (const float*)d_in[16];
  const float* conv_b = (const float*)d_in[17];
  const float* conv_w_b = (const float*)d_in[18];
  const float* conv_b_b = (const float*)d_in[19];
  const float* xproj_w = (const float*)d_in[20];
  const float* xproj_w_b = (const float*)d_in[21];
  const float *dt_w, *dt_bias, *dt_w_b, *dt_bias_b;
  if (in_sizes[23] == DEPTH_ * DI_ * RK_) {  // dict order: dt_w, dt_w_b, dt_b, dt_b_b
    dt_w = (const float*)d_in[22]; dt_w_b = (const float*)d_in[23];
    dt_bias = (const float*)d_in[24]; dt_bias_b = (const float*)d_in[25];
  } else {                                   // signature order
    dt_w = (const float*)d_in[22]; dt_bias = (const float*)d_in[23];
    dt_w_b = (const float*)d_in[24]; dt_bias_b = (const float*)d_in[25];
  }
  const float* A_log = (const float*)d_in[26];
  const float* A_log_b = (const float*)d_in[27];
  const float* D_par = (const float*)d_in[28];
  const float* D_par_b = (const float*)d_in[29];
  const float* out_w = (const float*)d_in[30];
  const int* vis_idx = (const int*)d_in[31];

  // ---------------- workspace layout (floats), lifetime-aliased: 61.1 MB ----------
  float* ws = (float*)d_ws;
  float* res   = ws;                 // 688128
  float* hbuf  = ws + 688128;        // 688128 (also: hloc during scan window)
  float* R1    = ws + 1376256;       // 2752512: partF+partB | yF+yB
  float* R2f   = ws + 4128768;       // 688128: hn_bf | dtr | Pb | ycb
  float* R3    = ws + 4816896;       // 2752512: xcFb+xcBb (ushort) | dtF+dtB (f32)
  float* xz    = ws + 7569408;       // 2752512 (x-stripes double as hstart buffer)
  float* xcF   = ws + 10321920;      // 1376256
  float* xcB   = ws + 11698176;      // 1376256
  float* projF = ws + 13074432;      // 71680
  float* projB = ws + 13146112;      // 71680
  float* wreg  = ws + 13217792;      // 2064384 f of bf16 weights

  // R1 views
  float* partF = R1;                         // 4*896*128
  float* partB = R1 + 458752;
  float* yF    = R1;                         // 896*1536
  float* yB    = R1 + 1376256;
  // phase-1 views
  float* tokv  = R1;                         // 1568*768
  float* toka  = R1 + 1204224;               // 192*768
  float* Aa    = R1 + 1351680;               // 192*256
  ushort_t* Av_bf = (ushort_t*)xz;           // 1568*768 bf16
  ushort_t* wPv   = (ushort_t*)xcF;          // 768*768 bf16
  // R2 views
  ushort_t* hn_bf = (ushort_t*)R2f;          // 896*768
  ushort_t* dtrF  = (ushort_t*)R2f;          // 896*64
  ushort_t* dtrB  = ((ushort_t*)R2f) + 57344;
  ushort_t* ycb   = (ushort_t*)R2f;          // 896*1536
  float* Pb       = R2f;                     // 6144*7*16 = 688128 (scan window)
  float* hloc     = hbuf;                    // 688128 (scan window: hbuf dead)
  // R3 views
  ushort_t* xcFb = (ushort_t*)R3;
  ushort_t* xcBb = ((ushort_t*)R3) + 1376256;
  float* dtF = R3;
  float* dtB = R3 + 1376256;
  // weight views
  ushort_t* wIn  = (ushort_t*)wreg;          // 3072*768
  ushort_t* wOut = wIn + 2359296;            // 768*1536
  ushort_t* wXF  = wOut + 1179648;           // 128*1536
  ushort_t* wXB  = wXF + 196608;
  ushort_t* wDF  = wXB + 196608;             // 1536*64
  ushort_t* wDB  = wDF + 98304;

  dim3 blk(256);

  // ---- phase 1: patch embed + assemble ----
  im2col_v<<<4704, blk, 0, stream>>>(x_v, Av_bf);
  cast_k<<<2304, blk, 0, stream>>>(patch_v_w, wPv, 589824);
  im2col_a<<<192, blk, 0, stream>>>(x_a, Aa);
  mfma_gemm<<<dim3(6, 13, 1), blk, 0, stream>>>(Av_bf, nullptr, 768, wPv, nullptr, 768,
                                                patch_v_b, nullptr, tokv, nullptr, 768,
                                                1568, 768, 1, 0, 0);
  gemm_nt<<<dim3(12, 3, 1), blk, 0, stream>>>(Aa, 256, patch_a_w, 256, patch_a_b,
                                              toka, 768, 192, 768, 256);
  assemble_k<<<2688, blk, 0, stream>>>(tokv, toka, pos_v, pos_a, tpos_v, tpos_a,
                                       cls_v, cls_a, glob_v, glob_a, vis_idx, hbuf, res);

  // ---- phase 2: 16 layers ----
  for (int l = 0; l < DEPTH_; ++l) {
    const float* nw  = norm_w + l * DD;
    const float* iw  = in_w + (size_t)l * 2 * DI_ * DD;
    const float* cw  = conv_w + l * DI_ * KC_;
    const float* cb  = conv_b + l * DI_;
    const float* cwb = conv_w_b + l * DI_ * KC_;
    const float* cbb = conv_b_b + l * DI_;
    const float* xw  = xproj_w + (size_t)l * 80 * DI_;
    const float* xwb = xproj_w_b + (size_t)l * 80 * DI_;
    const float* dw  = dt_w + (size_t)l * DI_ * RK_;
    const float* dbi = dt_bias + l * DI_;
    const float* dwb = dt_w_b + (size_t)l * DI_ * RK_;
    const float* dbib = dt_bias_b + l * DI_;
    const float* al  = A_log + (size_t)l * DI_ * NS_;
    const float* alb = A_log_b + (size_t)l * DI_ * NS_;
    const float* dp  = D_par + l * DI_;
    const float* dpb = D_par_b + l * DI_;
    const float* ow  = out_w + (size_t)l * DD * DI_;

    cast_layer_k<<<16128, blk, 0, stream>>>(iw, ow, xw, xwb, dw, dwb,
                                            wIn, wOut, wXF, wXB, wDF, wDB);
    rmsnorm_k<<<NROWS, blk, 0, stream>>>(hbuf, res, hn_bf, nw);
    mfma_gemm<<<dim3(24, 7, 1), blk, 0, stream>>>(hn_bf, nullptr, 768, wIn, nullptr, 768,
                                                  nullptr, nullptr, xz, nullptr, 3072,
                                                  NROWS, 768, 1, 0, 0);
    conv_k<<<5376, blk, 0, stream>>>(xz, cw, cb, cwb, cbb, xcF, xcB, xcFb, xcBb);
    mfma_gemm<<<dim3(1, 7, 8), blk, 0, stream>>>(xcFb, xcBb, 1536, wXF, wXB, 1536,
                                                 nullptr, nullptr, partF, partB, 128,
                                                 NROWS, 1536, 4, NROWS * 128, 0);
    reduce_pack_k<<<dim3(448, 2, 1), blk, 0, stream>>>(partF, partB, projF, projB, dtrF, dtrB);
    mfma_gemm<<<dim3(12, 7, 2), blk, 0, stream>>>(dtrF, dtrB, 64, wDF, wDB, 64,
                                                  dbi, dbib, dtF, dtB, 1536,
                                                  NROWS, 64, 1, 0, 1);
    // chunked scan: passA (chunks 0..5) -> hstart -> passB (all 7 chunks)
    scanA_k<<<dim3(192, NCH - 1, 2), blk, 0, stream>>>(xcF, dtF, projF, xcB, dtB, projB,
                                                       al, alb, hloc, Pb);
    hstart_k<<<384, blk, 0, stream>>>(hloc, Pb, xz);
    scanB_k<<<dim3(192, NCH, 2), blk, 0, stream>>>(xcF, dtF, projF, xcB, dtB, projB,
                                                   al, alb, dp, dpb, xz, yF, yB);
    combine_k<<<5376, blk, 0, stream>>>(yF, yB, xz, ycb);
    mfma_gemm<<<dim3(6, 7, 1), blk, 0, stream>>>(ycb, nullptr, 1536, wOut, nullptr, 1536,
                                                 nullptr, nullptr, hbuf, nullptr, 768,
                                                 NROWS, 1536, 1, 0, 0);
  }

  copy_k<<<2688, blk, 0, stream>>>(res, (float*)d_out, out_size);
}

// Round 4
// 3308.507 us; speedup vs baseline: 3.1013x; 1.1566x over previous
//
#include <hip/hip_runtime.h>
#include <math.h>

typedef unsigned short ushort_t;
typedef __attribute__((ext_vector_type(8))) short bf16x8;
typedef __attribute__((ext_vector_type(4))) float f32x4;

#define NBATCH 2
#define TT 4
#define DD 768
#define DI_ 1536
#define NS_ 16
#define RK_ 48
#define KC_ 4
#define DEPTH_ 16
#define LV 448
#define NROWS (NBATCH*LV)   // 896
#define NCH 7               // scan chunks
#define CLEN 64             // chunk length (7*64 = 448)
#define WLAYER 4128768      // ushorts of bf16 weights per layer

__device__ __forceinline__ float silu_f(float x) { return x / (1.f + __expf(-x)); }
__device__ __forceinline__ ushort_t f2bf(float x) {
  unsigned int u = __float_as_uint(x);
  return (ushort_t)((u + 0x7FFFu + ((u >> 16) & 1u)) >> 16);
}
__device__ __forceinline__ float bf2f(ushort_t h) {
  return __uint_as_float(((unsigned int)h) << 16);
}

typedef const __attribute__((address_space(1))) unsigned int* gas1_t;
typedef __attribute__((address_space(3))) unsigned int* las3_t;
__device__ __forceinline__ void gll16(const ushort_t* g, ushort_t* l) {
  __builtin_amdgcn_global_load_lds((gas1_t)g, (las3_t)l, 16, 0, 0);
}

// ===================== bf16 MFMA GEMM: C[M,N] = A[M,K] @ W[N,K]^T ==============
__global__ __launch_bounds__(256) void mfma_gemm(
    const ushort_t* __restrict__ A, const ushort_t* __restrict__ A2, int lda,
    const ushort_t* __restrict__ W, const ushort_t* __restrict__ W2, int ldw,
    const float* __restrict__ bias, const float* __restrict__ bias2,
    float* __restrict__ C, float* __restrict__ C2, int ldc,
    int M, int K, int nkChunks, long partStride, int epi)
{
  int z = blockIdx.z;
  int dir = z / nkChunks, chunk = z - dir * nkChunks;
  if (dir) { A = A2; W = W2; C = C2; bias = bias2; }
  int kChunk = K / nkChunks;
  int kbeg = chunk * kChunk;
  if (nkChunks > 1) C += (long)chunk * partStride;

  __shared__ __align__(16) ushort_t At[128 * 32];
  __shared__ __align__(16) ushort_t Bt[128 * 32];

  int tid = threadIdx.x, wv = tid >> 6, lane = tid & 63;
  int m0 = blockIdx.y * 128, n0 = blockIdx.x * 128;

  int S0 = wv * 128 + lane, S1 = S0 + 64;
  int r0 = S0 >> 2, g0 = (S0 & 3) ^ ((r0 >> 1) & 3);
  int r1 = S1 >> 2, g1 = (S1 & 3) ^ ((r1 >> 1) & 3);
  const ushort_t* a0 = A + (size_t)min(m0 + r0, M - 1) * lda + g0 * 8 + kbeg;
  const ushort_t* a1 = A + (size_t)min(m0 + r1, M - 1) * lda + g1 * 8 + kbeg;
  const ushort_t* b0 = W + (size_t)(n0 + r0) * ldw + g0 * 8 + kbeg;
  const ushort_t* b1 = W + (size_t)(n0 + r1) * ldw + g1 * 8 + kbeg;
  ushort_t* lA0 = At + S0 * 8; ushort_t* lA1 = At + S1 * 8;
  ushort_t* lB0 = Bt + S0 * 8; ushort_t* lB1 = Bt + S1 * 8;

  int wr = wv >> 1, wc = wv & 1;
  int rl = lane & 15, gl = lane >> 4;
  int offA[4], offB[4];
#pragma unroll
  for (int i = 0; i < 4; ++i) {
    int ra = wr * 64 + i * 16 + rl;
    offA[i] = ra * 32 + ((gl ^ ((ra >> 1) & 3)) * 8);
    int rb = wc * 64 + i * 16 + rl;
    offB[i] = rb * 32 + ((gl ^ ((rb >> 1) & 3)) * 8);
  }

  f32x4 acc[4][4] = {};
  int nk = kChunk >> 5;
  for (int t = 0; t < nk; ++t) {
    int ko = t << 5;
    gll16(a0 + ko, lA0); gll16(a1 + ko, lA1);
    gll16(b0 + ko, lB0); gll16(b1 + ko, lB1);
    __syncthreads();
    bf16x8 af[4], bw[4];
#pragma unroll
    for (int i = 0; i < 4; ++i) {
      af[i] = *(const bf16x8*)(At + offA[i]);
      bw[i] = *(const bf16x8*)(Bt + offB[i]);
    }
#pragma unroll
    for (int i = 0; i < 4; ++i)
#pragma unroll
      for (int j = 0; j < 4; ++j)
        acc[i][j] = __builtin_amdgcn_mfma_f32_16x16x32_bf16(af[i], bw[j], acc[i][j], 0, 0, 0);
    __syncthreads();
  }

#pragma unroll
  for (int i = 0; i < 4; ++i) {
    int row0 = m0 + wr * 64 + i * 16 + gl * 4;
#pragma unroll
    for (int q = 0; q < 4; ++q) {
      int row = row0 + q;
      if (row >= M) continue;
#pragma unroll
      for (int j = 0; j < 4; ++j) {
        int col = n0 + wc * 64 + j * 16 + rl;
        float v = acc[i][j][q];
        if (bias) v += bias[col];
        if (epi == 1) v = (v > 20.f) ? v : log1pf(__expf(v));
        C[(size_t)row * ldc + col] = v;
      }
    }
  }
}

// ===================== fp32 GEMM (audio patch only) =====================
__global__ __launch_bounds__(256) void gemm_nt(
    const float* __restrict__ A, int lda,
    const float* __restrict__ W, int ldw,
    const float* __restrict__ bias,
    float* __restrict__ C, int ldc, int M, int N, int K)
{
  __shared__ float As[16][68];
  __shared__ float Ws[16][68];
  int tid = threadIdx.x;
  int m0 = blockIdx.y * 64, n0 = blockIdx.x * 64;
  int ty = tid >> 4, tx = tid & 15;
  float acc[4][4] = {};
  for (int k0 = 0; k0 < K; k0 += 16) {
#pragma unroll
    for (int i = 0; i < 4; ++i) {
      int idx = tid + i * 256;
      int mm = idx >> 4, kk = idx & 15;
      int gm = m0 + mm, gk = k0 + kk;
      As[kk][mm] = (gm < M && gk < K) ? A[(size_t)gm * lda + gk] : 0.f;
      int gn = n0 + mm;
      Ws[kk][mm] = (gn < N && gk < K) ? W[(size_t)gn * ldw + gk] : 0.f;
    }
    __syncthreads();
#pragma unroll
    for (int kk = 0; kk < 16; ++kk) {
      float a[4], b[4];
#pragma unroll
      for (int i = 0; i < 4; ++i) a[i] = As[kk][ty * 4 + i];
#pragma unroll
      for (int j = 0; j < 4; ++j) b[j] = Ws[kk][tx * 4 + j];
#pragma unroll
      for (int i = 0; i < 4; ++i)
#pragma unroll
        for (int j = 0; j < 4; ++j) acc[i][j] = fmaf(a[i], b[j], acc[i][j]);
    }
    __syncthreads();
  }
#pragma unroll
  for (int i = 0; i < 4; ++i) {
    int gm = m0 + ty * 4 + i;
    if (gm >= M) continue;
#pragma unroll
    for (int j = 0; j < 4; ++j) {
      int gn = n0 + tx * 4 + j;
      if (gn >= N) continue;
      float v = acc[i][j];
      if (bias) v += bias[gn];
      C[(size_t)gm * ldc + gn] = v;
    }
  }
}

// ===================== weight casts =====================
__global__ __launch_bounds__(256) void cast_k(const float* __restrict__ s, ushort_t* __restrict__ d, int n)
{
  int i = blockIdx.x * 256 + threadIdx.x;
  if (i < n) d[i] = f2bf(s[i]);
}

__device__ __forceinline__ void cast_one(
    int j, const float* iw, const float* ow, const float* xw, const float* xwb,
    const float* dw, const float* dwb, ushort_t* wb)
{
  if (j < 2359296) { wb[j] = f2bf(iw[j]); return; }
  int j0 = j; j -= 2359296;
  if (j < 1179648) { wb[j0] = f2bf(ow[j]); return; } j -= 1179648;
  if (j < 196608) { int r = j / 1536, k = j - r * 1536;
    wb[j0] = f2bf(r < 80 ? xw[r * 1536 + k] : 0.f); return; } j -= 196608;
  if (j < 196608) { int r = j / 1536, k = j - r * 1536;
    wb[j0] = f2bf(r < 80 ? xwb[r * 1536 + k] : 0.f); return; } j -= 196608;
  if (j < 98304) { int d = j >> 6, k = j & 63;
    wb[j0] = f2bf(k < 48 ? dw[d * 48 + k] : 0.f); return; } j -= 98304;
  int d = j >> 6, k = j & 63;
  wb[j0] = f2bf(k < 48 ? dwb[d * 48 + k] : 0.f);
}

__global__ __launch_bounds__(256) void cast_all_k(
    const float* __restrict__ iw0, const float* __restrict__ ow0,
    const float* __restrict__ xw0, const float* __restrict__ xwb0,
    const float* __restrict__ dw0, const float* __restrict__ dwb0,
    ushort_t* __restrict__ wall)
{
  int i = blockIdx.x * 256 + threadIdx.x;
  if (i >= DEPTH_ * WLAYER) return;
  int l = i / WLAYER, j = i - l * WLAYER;
  cast_one(j, iw0 + (size_t)l * 2359296, ow0 + (size_t)l * 1179648,
           xw0 + (size_t)l * 122880, xwb0 + (size_t)l * 122880,
           dw0 + (size_t)l * 73728, dwb0 + (size_t)l * 73728,
           wall + (size_t)l * WLAYER);
}

__global__ __launch_bounds__(256) void cast_layer_k(
    const float* __restrict__ iw, const float* __restrict__ ow,
    const float* __restrict__ xw, const float* __restrict__ xwb,
    const float* __restrict__ dw, const float* __restrict__ dwb,
    ushort_t* __restrict__ wb)
{
  int j = blockIdx.x * 256 + threadIdx.x;
  if (j < WLAYER) cast_one(j, iw, ow, xw, xwb, dw, dwb, wb);
}

// ===================== im2col =====================
__global__ __launch_bounds__(256) void im2col_v(const float* __restrict__ xv, ushort_t* __restrict__ Av)
{
  int i = blockIdx.x * 256 + threadIdx.x;
  if (i >= 1568 * 768) return;
  int m = i / 768, k = i % 768;
  int c = k >> 8, r = k & 255;
  int kh = r >> 4, kw = r & 15;
  int bt = m / 196, n = m % 196;
  int b = bt / TT, t = bt % TT;
  int hb = n / 14, wb = n % 14;
  Av[i] = f2bf(xv[(size_t)b * 602112 + (size_t)c * 200704 + t * 50176 + (hb * 16 + kh) * 224 + wb * 16 + kw]);
}

__global__ __launch_bounds__(256) void im2col_a(const float* __restrict__ xa, float* __restrict__ Aa)
{
  int i = blockIdx.x * 256 + threadIdx.x;
  if (i >= 192 * 256) return;
  int m = i / 256, k = i % 256;
  int kh = k >> 4, kw = k & 15;
  int b = m / 96, q = m % 96;
  int tb = q >> 2, fb = q & 3;
  Aa[i] = xa[(size_t)b * 24576 + (fb * 16 + kw) * 384 + tb * 16 + kh];
}

// ===================== assemble tokens + gather =====================
__global__ __launch_bounds__(256) void assemble_k(
    const float* __restrict__ tokv, const float* __restrict__ toka,
    const float* __restrict__ pos_v, const float* __restrict__ pos_a,
    const float* __restrict__ tpos_v, const float* __restrict__ tpos_a,
    const float* __restrict__ cls_v, const float* __restrict__ cls_a,
    const float* __restrict__ glob_v, const float* __restrict__ glob_a,
    const int* __restrict__ vis_idx,
    float* __restrict__ h, float* __restrict__ res)
{
  int i = blockIdx.x * 256 + threadIdx.x;
  if (i >= NROWS * DD) return;
  int d = i % DD;
  int bl = i / DD;
  int r = bl % LV, b = bl / LV;
  int tok = vis_idx[b * LV + r];
  int t = tok / 224, q = tok % 224;
  float v;
  if (q == 0) v = cls_v[d];
  else if (q <= 196) {
    int n = q - 1;
    v = tokv[((size_t)(b * TT + t) * 196 + n) * DD + d] + pos_v[n * DD + d] + tpos_v[t * DD + d];
  } else if (q == 197) v = glob_v[d];
  else if (q == 198) v = cls_a[d];
  else if (q <= 222) {
    int n = q - 199;
    v = toka[((size_t)b * 96 + t * 24 + n) * DD + d] + pos_a[n * DD + d] + tpos_a[t * DD + d];
  } else v = glob_a[d];
  h[i] = v;
  res[i] = 0.f;
}

// ===================== fused residual add + RMSNorm (bf16 out) =====================
__global__ __launch_bounds__(256) void rmsnorm_k(
    const float* __restrict__ h, float* __restrict__ res,
    ushort_t* __restrict__ hn, const float* __restrict__ nw)
{
  int row = blockIdx.x;
  const float* hp = h + (size_t)row * DD;
  float* rp = res + (size_t)row * DD;
  ushort_t* op = hn + (size_t)row * DD;
  int tid = threadIdx.x;
  float v[3];
  float ss = 0.f;
#pragma unroll
  for (int i = 0; i < 3; ++i) {
    float x = hp[tid + i * 256] + rp[tid + i * 256];
    v[i] = x;
    ss += x * x;
  }
  for (int m = 1; m < 64; m <<= 1) ss += __shfl_xor(ss, m, 64);
  __shared__ float sred[4];
  if ((tid & 63) == 0) sred[tid >> 6] = ss;
  __syncthreads();
  float tot = sred[0] + sred[1] + sred[2] + sred[3];
  float sc = rsqrtf(tot / (float)DD + 1e-5f);
#pragma unroll
  for (int i = 0; i < 3; ++i) {
    int c = tid + i * 256;
    rp[c] = v[i];
    op[c] = f2bf(v[i] * sc * nw[c]);
  }
}

// ===================== causal depthwise conv (k=4) + silu -> bf16 =============
__global__ __launch_bounds__(256) void conv_k(
    const float* __restrict__ xz,
    const float* __restrict__ cw, const float* __restrict__ cb,
    const float* __restrict__ cwb, const float* __restrict__ cbb,
    ushort_t* __restrict__ xcFb, ushort_t* __restrict__ xcBb)
{
  int i = blockIdx.x * 256 + threadIdx.x;
  if (i >= NROWS * DI_) return;
  int d = i % DI_;
  int bl = i / DI_;
  int l = bl % LV, b = bl / LV;
  const float* xzb = xz + (size_t)b * LV * (2 * DI_);
  float accf = cb[d];
#pragma unroll
  for (int j = 0; j < 4; ++j) {
    int lp = l - 3 + j;
    if (lp >= 0) accf += xzb[(size_t)lp * (2 * DI_) + d] * cw[d * 4 + j];
  }
  float accb = cbb[d];
#pragma unroll
  for (int j = 0; j < 4; ++j) {
    int lp = l - 3 + j;
    if (lp >= 0) accb += xzb[(size_t)(LV - 1 - lp) * (2 * DI_) + d] * cwb[d * 4 + j];
  }
  xcFb[i] = f2bf(silu_f(accf));
  xcBb[i] = f2bf(silu_f(accb));
}

// ===================== split-K reduce (8 chunks) + dtr bf16 pack ==============
__global__ __launch_bounds__(256) void reduce_pack_k(
    const float* __restrict__ pF, const float* __restrict__ pB,
    float* __restrict__ prF, float* __restrict__ prB,
    ushort_t* __restrict__ dF, ushort_t* __restrict__ dB)
{
  int i = blockIdx.x * 256 + threadIdx.x;   // over 896*128
  if (i >= NROWS * 128) return;
  int dir = blockIdx.y;
  const float* part = dir ? pB : pF;
  float* proj = dir ? prB : prF;
  ushort_t* dtr = dir ? dB : dF;
  int row = i >> 7, col = i & 127;
  float s = 0.f;
  if (col < 80) {
#pragma unroll
    for (int c = 0; c < 8; ++c) s += part[c * (NROWS * 128) + i];
    proj[row * 80 + col] = s;
  }
  if (col < 64) dtr[(row << 6) + col] = f2bf(col < 48 ? s : 0.f);
}

// ===================== split-K reduce for out-proj ==============
__global__ __launch_bounds__(256) void reduce_out_k(
    const float* __restrict__ part, float* __restrict__ out)
{
  int i = blockIdx.x * 256 + threadIdx.x;
  if (i >= NROWS * DD) return;
  float s = 0.f;
#pragma unroll
  for (int c = 0; c < 4; ++c) s += part[c * (NROWS * DD) + i];
  out[i] = s;
}

// ===================== chunked selective scan =====================
// pass A: chunks 0..5, local state from 0 and decay P = exp(An * sum dt)
__global__ __launch_bounds__(256) void scanA_k(
    const ushort_t* __restrict__ xcFb, const float* __restrict__ dtF, const float* __restrict__ prF,
    const ushort_t* __restrict__ xcBb, const float* __restrict__ dtB, const float* __restrict__ prB,
    const float* __restrict__ AlF, const float* __restrict__ AlB,
    float* __restrict__ hloc, float* __restrict__ Pb)
{
  int dir = blockIdx.z;
  const ushort_t* xc = dir ? xcBb : xcFb;
  const float* dt = dir ? dtB : dtF;
  const float* pr = dir ? prB : prF;
  const float* Al = dir ? AlB : AlF;
  int c = blockIdx.y;
  int g = blockIdx.x * 16 + (threadIdx.x >> 4);
  int n = threadIdx.x & 15;
  int b = g / DI_, d = g % DI_;
  float An = -__expf(Al[d * NS_ + n]);
  const ushort_t* xcp = xc + (size_t)b * LV * DI_ + d;
  const float* dtp = dt + (size_t)b * LV * DI_ + d;
  const float* prp = pr + (size_t)b * LV * 80;
  int l0 = c * CLEN;
  float hs = 0.f, S = 0.f;
  float dtv = dtp[(size_t)l0 * DI_];
  float xcv = bf2f(xcp[(size_t)l0 * DI_]);
  float bn  = prp[l0 * 80 + 48 + n];
  for (int kk = 0; kk < CLEN; ++kk) {
    float dtv_n = 0.f, xcv_n = 0.f, bn_n = 0.f;
    if (kk < CLEN - 1) {
      int l1 = l0 + kk + 1;
      dtv_n = dtp[(size_t)l1 * DI_];
      xcv_n = bf2f(xcp[(size_t)l1 * DI_]);
      bn_n  = prp[l1 * 80 + 48 + n];
    }
    hs = __expf(dtv * An) * hs + dtv * bn * xcv;
    S += dtv;
    dtv = dtv_n; xcv = xcv_n; bn = bn_n;
  }
  int idx = ((dir * 3072 + g) * 6 + c) * NS_ + n;
  hloc[idx] = hs;
  Pb[idx] = __expf(An * S);
}

// pass BC: both dirs in parallel warps; in-block h_start prefix; fused combine.
// tid: n=tid&15, gi=(tid>>4)&7, dir=tid>>7. grid (384, 7).
__global__ __launch_bounds__(256) void scanBC_k(
    const ushort_t* __restrict__ xcFb, const float* __restrict__ dtF, const float* __restrict__ prF,
    const ushort_t* __restrict__ xcBb, const float* __restrict__ dtB, const float* __restrict__ prB,
    const float* __restrict__ AlF, const float* __restrict__ AlB,
    const float* __restrict__ DpF, const float* __restrict__ DpB,
    const float* __restrict__ hloc, const float* __restrict__ Pb,
    const float* __restrict__ xz, ushort_t* __restrict__ yc)
{
  int c = blockIdx.y;                 // fwd chunk index
  int tid = threadIdx.x;
  int n = tid & 15, gi = (tid >> 4) & 7, dir = tid >> 7;
  int g = blockIdx.x * 8 + gi;
  int b = g / DI_, d = g % DI_;
  __shared__ float sbuf[2][8][64];

  const ushort_t* xc = dir ? xcBb : xcFb;
  const float* dt = dir ? dtB : dtF;
  const float* pr = dir ? prB : prF;
  const float* Al = dir ? AlB : AlF;
  const float* Dpp = dir ? DpB : DpF;
  int myc = dir ? (6 - c) : c;        // chunk in own time direction
  float An = -__expf(Al[d * NS_ + n]);
  float Dpd = Dpp[d];
  // h_start prefix from pass-A results
  float hs = 0.f;
  for (int j = 0; j < myc; ++j) {
    int idx = ((dir * 3072 + g) * 6 + j) * NS_ + n;
    hs = Pb[idx] * hs + hloc[idx];
  }
  const ushort_t* xcp = xc + (size_t)b * LV * DI_ + d;
  const float* dtp = dt + (size_t)b * LV * DI_ + d;
  const float* prp = pr + (size_t)b * LV * 80;
  int l0 = myc * CLEN;
  float dtv = dtp[(size_t)l0 * DI_];
  float xcv = bf2f(xcp[(size_t)l0 * DI_]);
  float bn  = prp[l0 * 80 + 48 + n];
  float cn  = prp[l0 * 80 + 64 + n];
  for (int kk = 0; kk < CLEN; ++kk) {
    float dtv_n = 0.f, xcv_n = 0.f, bn_n = 0.f, cn_n = 0.f;
    if (kk < CLEN - 1) {
      int l1 = l0 + kk + 1;
      dtv_n = dtp[(size_t)l1 * DI_];
      xcv_n = bf2f(xcp[(size_t)l1 * DI_]);
      bn_n  = prp[l1 * 80 + 48 + n];
      cn_n  = prp[l1 * 80 + 64 + n];
    }
    hs = __expf(dtv * An) * hs + dtv * bn * xcv;
    float p = hs * cn;
    p += __shfl_xor(p, 1, 16);
    p += __shfl_xor(p, 2, 16);
    p += __shfl_xor(p, 4, 16);
    p += __shfl_xor(p, 8, 16);
    if (n == 0) {
      int off = dir ? (CLEN - 1 - kk) : kk;   // B outputs land at mirrored fwd offset
      sbuf[dir][gi][off] = p + xcv * Dpd;
    }
    dtv = dtv_n; xcv = xcv_n; bn = bn_n; cn = cn_n;
  }
  __syncthreads();
  // combine: (yF + yBrev) * silu(z) -> bf16, 2 outputs/thread
  for (int oid = tid; oid < 512; oid += 256) {
    int gi2 = oid >> 6, kk = oid & 63;
    int g2 = blockIdx.x * 8 + gi2;
    int b2 = g2 / DI_, d2 = g2 % DI_;
    int l = c * CLEN + kk;
    float z = xz[((size_t)b2 * LV + l) * 3072 + 1536 + d2];
    float v = (sbuf[0][gi2][kk] + sbuf[1][gi2][kk]) * silu_f(z);
    yc[((size_t)b2 * LV + l) * DI_ + d2] = f2bf(v);
  }
}

__global__ __launch_bounds__(256) void copy_k(const float* __restrict__ src, float* __restrict__ dst, int n)
{
  int i = blockIdx.x * 256 + threadIdx.x;
  if (i < n) dst[i] = src[i];
}

extern "C" void kernel_launch(void* const* d_in, const int* in_sizes, int n_in,
                              void* d_out, int out_size, void* d_ws, size_t ws_size,
                              hipStream_t stream)
{
  const float* x_v = (const float*)d_in[0];
  const float* x_a = (const float*)d_in[1];
  const float* patch_v_w = (const float*)d_in[2];
  const float* patch_v_b = (const float*)d_in[3];
  const float* patch_a_w = (const float*)d_in[4];
  const float* patch_a_b = (const float*)d_in[5];
  const float* pos_v = (const float*)d_in[6];
  const float* pos_a = (const float*)d_in[7];
  const float* tpos_v = (const float*)d_in[8];
  const float* tpos_a = (const float*)d_in[9];
  const float* cls_v = (const float*)d_in[10];
  const float* cls_a = (const float*)d_in[11];
  const float* glob_v = (const float*)d_in[12];
  const float* glob_a = (const float*)d_in[13];
  const float* norm_w = (const float*)d_in[14];
  const float* in_w = (const float*)d_in[15];
  const float* conv_w = (const float*)d_in[16];
  const float* conv_b = (const float*)d_in[17];
  const float* conv_w_b = (const float*)d_in[18];
  const float* conv_b_b = (const float*)d_in[19];
  const float* xproj_w = (const float*)d_in[20];
  const float* xproj_w_b = (const float*)d_in[21];
  const float *dt_w, *dt_bias, *dt_w_b, *dt_bias_b;
  if (in_sizes[23] == DEPTH_ * DI_ * RK_) {  // dict order: dt_w, dt_w_b, dt_b, dt_b_b
    dt_w = (const float*)d_in[22]; dt_w_b = (const float*)d_in[23];
    dt_bias = (const float*)d_in[24]; dt_bias_b = (const float*)d_in[25];
  } else {                                   // signature order
    dt_w = (const float*)d_in[22]; dt_bias = (const float*)d_in[23];
    dt_w_b = (const float*)d_in[24]; dt_bias_b = (const float*)d_in[25];
  }
  const float* A_log = (const float*)d_in[26];
  const float* A_log_b = (const float*)d_in[27];
  const float* D_par = (const float*)d_in[28];
  const float* D_par_b = (const float*)d_in[29];
  const float* out_w = (const float*)d_in[30];
  const int* vis_idx = (const int*)d_in[31];

  // ---------------- workspace layout (float units) ----------------
  float* ws = (float*)d_ws;
  float* res   = ws;                 // 688128
  float* hbuf  = ws + 688128;        // 688128
  float* R1    = ws + 1376256;       // 2752512: phase1 | xproj partials | hloc+Pb | outproj partials
  float* R2f   = ws + 4128768;       // 688128: hn_bf | dtrF/dtrB | ycb
  float* R3    = ws + 4816896;       // 1376256: xcFb + xcBb (bf16)
  float* xz    = ws + 7569408;       // 2752512 (phase1: Av_bf alias)
  float* dtF   = ws + 10321920;      // 1376256
  float* dtB   = ws + 11698176;      // 1376256
  float* projF = ws + 13074432;      // 71680
  float* projB = ws + 13146112;      // 71680
  float* wPvf  = ws + 13217792;      // 294912 (589824 bf16)
  float* WALLf = ws + 13512704;      // big path: 16*WLAYER ushorts = 33030144 floats

  // R1 views
  float* partF = R1;                         // 8*896*128 = 917504
  float* partB = R1 + 917504;
  float* hloc  = R1;                         // 589824
  float* Pb    = R1 + 589824;                // 589824
  float* partO = R1;                         // 4*688128 = 2752512
  // phase-1 views
  float* tokv  = R1;                         // 1568*768
  float* toka  = R1 + 1204224;               // 192*768
  float* Aa    = R1 + 1351680;               // 192*256
  ushort_t* Av_bf = (ushort_t*)xz;           // 1568*768 bf16
  ushort_t* wPv   = (ushort_t*)wPvf;
  // R2 views
  ushort_t* hn_bf = (ushort_t*)R2f;          // 896*768
  ushort_t* dtrF  = (ushort_t*)R2f;          // 896*64
  ushort_t* dtrB  = ((ushort_t*)R2f) + 57344;
  ushort_t* ycb   = (ushort_t*)R2f;          // 896*1536
  // R3 views
  ushort_t* xcFb = (ushort_t*)R3;            // 896*1536
  ushort_t* xcBb = ((ushort_t*)R3) + 1376256;

  size_t need_big = ((size_t)13512704 + 33030144) * 4;
  int bigws = ws_size >= need_big;
  ushort_t* WALL = (ushort_t*)WALLf;

  dim3 blk(256);

  // ---- weight pre-cast (all layers at once if ws allows) ----
  if (bigws)
    cast_all_k<<<(DEPTH_ * WLAYER + 255) / 256, blk, 0, stream>>>(
        in_w, out_w, xproj_w, xproj_w_b, dt_w, dt_w_b, WALL);

  // ---- phase 1: patch embed + assemble ----
  im2col_v<<<4704, blk, 0, stream>>>(x_v, Av_bf);
  cast_k<<<2304, blk, 0, stream>>>(patch_v_w, wPv, 589824);
  im2col_a<<<192, blk, 0, stream>>>(x_a, Aa);
  mfma_gemm<<<dim3(6, 13, 1), blk, 0, stream>>>(Av_bf, nullptr, 768, wPv, nullptr, 768,
                                                patch_v_b, nullptr, tokv, nullptr, 768,
                                                1568, 768, 1, 0, 0);
  gemm_nt<<<dim3(12, 3, 1), blk, 0, stream>>>(Aa, 256, patch_a_w, 256, patch_a_b,
                                              toka, 768, 192, 768, 256);
  assemble_k<<<2688, blk, 0, stream>>>(tokv, toka, pos_v, pos_a, tpos_v, tpos_a,
                                       cls_v, cls_a, glob_v, glob_a, vis_idx, hbuf, res);

  // ---- phase 2: 16 layers ----
  for (int l = 0; l < DEPTH_; ++l) {
    const float* nw  = norm_w + l * DD;
    const float* cw  = conv_w + l * DI_ * KC_;
    const float* cb  = conv_b + l * DI_;
    const float* cwb = conv_w_b + l * DI_ * KC_;
    const float* cbb = conv_b_b + l * DI_;
    const float* dbi = dt_bias + l * DI_;
    const float* dbib = dt_bias_b + l * DI_;
    const float* al  = A_log + (size_t)l * DI_ * NS_;
    const float* alb = A_log_b + (size_t)l * DI_ * NS_;
    const float* dp  = D_par + l * DI_;
    const float* dpb = D_par_b + l * DI_;

    ushort_t* wb = bigws ? (WALL + (size_t)l * WLAYER) : WALL;
    if (!bigws)
      cast_layer_k<<<(WLAYER + 255) / 256, blk, 0, stream>>>(
          in_w + (size_t)l * 2359296, out_w + (size_t)l * 1179648,
          xproj_w + (size_t)l * 122880, xproj_w_b + (size_t)l * 122880,
          dt_w + (size_t)l * 73728, dt_w_b + (size_t)l * 73728, wb);
    ushort_t* wIn  = wb;
    ushort_t* wOut = wIn + 2359296;
    ushort_t* wXF  = wOut + 1179648;
    ushort_t* wXB  = wXF + 196608;
    ushort_t* wDF  = wXB + 196608;
    ushort_t* wDB  = wDF + 98304;

    rmsnorm_k<<<NROWS, blk, 0, stream>>>(hbuf, res, hn_bf, nw);
    // in-proj: [896,3072] = hn @ in_w^T
    mfma_gemm<<<dim3(24, 7, 1), blk, 0, stream>>>(hn_bf, nullptr, 768, wIn, nullptr, 768,
                                                  nullptr, nullptr, xz, nullptr, 3072,
                                                  NROWS, 768, 1, 0, 0);
    conv_k<<<5376, blk, 0, stream>>>(xz, cw, cb, cwb, cbb, xcFb, xcBb);
    // xproj both dirs, split-K x8
    mfma_gemm<<<dim3(1, 7, 16), blk, 0, stream>>>(xcFb, xcBb, 1536, wXF, wXB, 1536,
                                                  nullptr, nullptr, partF, partB, 128,
                                                  NROWS, 1536, 8, NROWS * 128, 0);
    reduce_pack_k<<<dim3(448, 2, 1), blk, 0, stream>>>(partF, partB, projF, projB, dtrF, dtrB);
    // dt both dirs: softplus(dtr @ dtw^T + b)
    mfma_gemm<<<dim3(12, 7, 2), blk, 0, stream>>>(dtrF, dtrB, 64, wDF, wDB, 64,
                                                  dbi, dbib, dtF, dtB, 1536,
                                                  NROWS, 64, 1, 0, 1);
    // chunked scan: passA then fused passB+combine
    scanA_k<<<dim3(192, 6, 2), blk, 0, stream>>>(xcFb, dtF, projF, xcBb, dtB, projB,
                                                 al, alb, hloc, Pb);
    scanBC_k<<<dim3(384, NCH, 1), blk, 0, stream>>>(xcFb, dtF, projF, xcBb, dtB, projB,
                                                    al, alb, dp, dpb, hloc, Pb, xz, ycb);
    // out-proj split-K x4: [896,768] = yc @ out_w^T
    mfma_gemm<<<dim3(6, 7, 4), blk, 0, stream>>>(ycb, nullptr, 1536, wOut, nullptr, 1536,
                                                 nullptr, nullptr, partO, nullptr, 768,
                                                 NROWS, 1536, 4, NROWS * DD, 0);
    reduce_out_k<<<2688, blk, 0, stream>>>(partO, hbuf);
  }

  copy_k<<<2688, blk, 0, stream>>>(res, (float*)d_out, out_size);
}

// Round 5
// 3130.126 us; speedup vs baseline: 3.2781x; 1.0570x over previous
//
#include <hip/hip_runtime.h>
#include <math.h>

typedef unsigned short ushort_t;
typedef __attribute__((ext_vector_type(8))) short bf16x8;
typedef __attribute__((ext_vector_type(4))) float f32x4;
typedef __attribute__((ext_vector_type(4))) unsigned short us4;

#define NBATCH 2
#define TT 4
#define DD 768
#define DI_ 1536
#define NS_ 16
#define RK_ 48
#define KC_ 4
#define DEPTH_ 16
#define NRUN 15             // layer 16's compute is dead (only res += h survives)
#define LV 448
#define NROWS (NBATCH*LV)   // 896
#define NCH 7               // scan chunks
#define CLEN 64             // chunk length (7*64 = 448)
#define WLAYER 4128768      // ushorts of bf16 weights per layer
#define WL4 (WLAYER/4)

__device__ __forceinline__ float silu_f(float x) { return x / (1.f + __expf(-x)); }
__device__ __forceinline__ ushort_t f2bf(float x) {
  unsigned int u = __float_as_uint(x);
  return (ushort_t)((u + 0x7FFFu + ((u >> 16) & 1u)) >> 16);
}
__device__ __forceinline__ float bf2f(ushort_t h) {
  return __uint_as_float(((unsigned int)h) << 16);
}

typedef const __attribute__((address_space(1))) unsigned int* gas1_t;
typedef __attribute__((address_space(3))) unsigned int* las3_t;
__device__ __forceinline__ void gll16(const ushort_t* g, ushort_t* l) {
  __builtin_amdgcn_global_load_lds((gas1_t)g, (las3_t)l, 16, 0, 0);
}

// ===================== bf16 MFMA GEMM: C[M,N] = A[M,K] @ W[N,K]^T ==============
// epi: 0 = f32 out (+bias), 1 = f32 softplus(acc+bias), 2 = bf16 out
__global__ __launch_bounds__(256) void mfma_gemm(
    const ushort_t* __restrict__ A, const ushort_t* __restrict__ A2, int lda,
    const ushort_t* __restrict__ W, const ushort_t* __restrict__ W2, int ldw,
    const float* __restrict__ bias, const float* __restrict__ bias2,
    float* __restrict__ C, float* __restrict__ C2, int ldc,
    int M, int K, int nkChunks, long partStride, int epi)
{
  int z = blockIdx.z;
  int dir = z / nkChunks, chunk = z - dir * nkChunks;
  if (dir) { A = A2; W = W2; C = C2; bias = bias2; }
  int kChunk = K / nkChunks;
  int kbeg = chunk * kChunk;
  if (nkChunks > 1) C += (long)chunk * partStride;

  __shared__ __align__(16) ushort_t At[128 * 32];
  __shared__ __align__(16) ushort_t Bt[128 * 32];

  int tid = threadIdx.x, wv = tid >> 6, lane = tid & 63;
  int m0 = blockIdx.y * 128, n0 = blockIdx.x * 128;

  int S0 = wv * 128 + lane, S1 = S0 + 64;
  int r0 = S0 >> 2, g0 = (S0 & 3) ^ ((r0 >> 1) & 3);
  int r1 = S1 >> 2, g1 = (S1 & 3) ^ ((r1 >> 1) & 3);
  const ushort_t* a0 = A + (size_t)min(m0 + r0, M - 1) * lda + g0 * 8 + kbeg;
  const ushort_t* a1 = A + (size_t)min(m0 + r1, M - 1) * lda + g1 * 8 + kbeg;
  const ushort_t* b0 = W + (size_t)(n0 + r0) * ldw + g0 * 8 + kbeg;
  const ushort_t* b1 = W + (size_t)(n0 + r1) * ldw + g1 * 8 + kbeg;
  ushort_t* lA0 = At + S0 * 8; ushort_t* lA1 = At + S1 * 8;
  ushort_t* lB0 = Bt + S0 * 8; ushort_t* lB1 = Bt + S1 * 8;

  int wr = wv >> 1, wc = wv & 1;
  int rl = lane & 15, gl = lane >> 4;
  int offA[4], offB[4];
#pragma unroll
  for (int i = 0; i < 4; ++i) {
    int ra = wr * 64 + i * 16 + rl;
    offA[i] = ra * 32 + ((gl ^ ((ra >> 1) & 3)) * 8);
    int rb = wc * 64 + i * 16 + rl;
    offB[i] = rb * 32 + ((gl ^ ((rb >> 1) & 3)) * 8);
  }

  f32x4 acc[4][4] = {};
  int nk = kChunk >> 5;
  for (int t = 0; t < nk; ++t) {
    int ko = t << 5;
    gll16(a0 + ko, lA0); gll16(a1 + ko, lA1);
    gll16(b0 + ko, lB0); gll16(b1 + ko, lB1);
    __syncthreads();
    bf16x8 af[4], bw[4];
#pragma unroll
    for (int i = 0; i < 4; ++i) {
      af[i] = *(const bf16x8*)(At + offA[i]);
      bw[i] = *(const bf16x8*)(Bt + offB[i]);
    }
#pragma unroll
    for (int i = 0; i < 4; ++i)
#pragma unroll
      for (int j = 0; j < 4; ++j)
        acc[i][j] = __builtin_amdgcn_mfma_f32_16x16x32_bf16(af[i], bw[j], acc[i][j], 0, 0, 0);
    __syncthreads();
  }

#pragma unroll
  for (int i = 0; i < 4; ++i) {
    int row0 = m0 + wr * 64 + i * 16 + gl * 4;
#pragma unroll
    for (int q = 0; q < 4; ++q) {
      int row = row0 + q;
      if (row >= M) continue;
#pragma unroll
      for (int j = 0; j < 4; ++j) {
        int col = n0 + wc * 64 + j * 16 + rl;
        float v = acc[i][j][q];
        if (bias) v += bias[col];
        if (epi == 1) v = (v > 20.f) ? v : log1pf(__expf(v));
        if (epi == 2) ((ushort_t*)C)[(size_t)row * ldc + col] = f2bf(v);
        else C[(size_t)row * ldc + col] = v;
      }
    }
  }
}

// ===================== fp32 GEMM (audio patch only) =====================
__global__ __launch_bounds__(256) void gemm_nt(
    const float* __restrict__ A, int lda,
    const float* __restrict__ W, int ldw,
    const float* __restrict__ bias,
    float* __restrict__ C, int ldc, int M, int N, int K)
{
  __shared__ float As[16][68];
  __shared__ float Ws[16][68];
  int tid = threadIdx.x;
  int m0 = blockIdx.y * 64, n0 = blockIdx.x * 64;
  int ty = tid >> 4, tx = tid & 15;
  float acc[4][4] = {};
  for (int k0 = 0; k0 < K; k0 += 16) {
#pragma unroll
    for (int i = 0; i < 4; ++i) {
      int idx = tid + i * 256;
      int mm = idx >> 4, kk = idx & 15;
      int gm = m0 + mm, gk = k0 + kk;
      As[kk][mm] = (gm < M && gk < K) ? A[(size_t)gm * lda + gk] : 0.f;
      int gn = n0 + mm;
      Ws[kk][mm] = (gn < N && gk < K) ? W[(size_t)gn * ldw + gk] : 0.f;
    }
    __syncthreads();
#pragma unroll
    for (int kk = 0; kk < 16; ++kk) {
      float a[4], b[4];
#pragma unroll
      for (int i = 0; i < 4; ++i) a[i] = As[kk][ty * 4 + i];
#pragma unroll
      for (int j = 0; j < 4; ++j) b[j] = Ws[kk][tx * 4 + j];
#pragma unroll
      for (int i = 0; i < 4; ++i)
#pragma unroll
        for (int j = 0; j < 4; ++j) acc[i][j] = fmaf(a[i], b[j], acc[i][j]);
    }
    __syncthreads();
  }
#pragma unroll
  for (int i = 0; i < 4; ++i) {
    int gm = m0 + ty * 4 + i;
    if (gm >= M) continue;
#pragma unroll
    for (int j = 0; j < 4; ++j) {
      int gn = n0 + tx * 4 + j;
      if (gn >= N) continue;
      float v = acc[i][j];
      if (bias) v += bias[gn];
      C[(size_t)gm * ldc + gn] = v;
    }
  }
}

// ===================== vectorized weight casts =====================
__global__ __launch_bounds__(256) void cast4_k(const float* __restrict__ s, ushort_t* __restrict__ d, int n4)
{
  int i = blockIdx.x * 256 + threadIdx.x;
  if (i >= n4) return;
  f32x4 v = *(const f32x4*)(s + i * 4);
  us4 o = { f2bf(v[0]), f2bf(v[1]), f2bf(v[2]), f2bf(v[3]) };
  *(us4*)(d + i * 4) = o;
}

// per-layer WALL block: [wIn 2359296 | wOut 1179648 | wXF 196608 | wXB 196608 | wDF 98304 | wDB 98304]
__global__ __launch_bounds__(256) void cast_all4_k(
    const float* __restrict__ iw0, const float* __restrict__ ow0,
    const float* __restrict__ xw0, const float* __restrict__ xwb0,
    const float* __restrict__ dw0, const float* __restrict__ dwb0,
    ushort_t* __restrict__ wall, int nl)
{
  int i = blockIdx.x * 256 + threadIdx.x;
  if (i >= nl * WL4) return;
  int l = i / WL4;
  int j = (i - l * WL4) * 4;
  const float* iw  = iw0  + (size_t)l * 2359296;
  const float* ow  = ow0  + (size_t)l * 1179648;
  const float* xw  = xw0  + (size_t)l * 122880;
  const float* xwb = xwb0 + (size_t)l * 122880;
  const float* dw  = dw0  + (size_t)l * 73728;
  const float* dwb = dwb0 + (size_t)l * 73728;
  ushort_t* wb = wall + (size_t)l * WLAYER + j;
  f32x4 v = {0.f, 0.f, 0.f, 0.f};
  int j2 = j;
  if (j2 < 2359296) v = *(const f32x4*)(iw + j2);
  else {
    j2 -= 2359296;
    if (j2 < 1179648) v = *(const f32x4*)(ow + j2);
    else {
      j2 -= 1179648;
      if (j2 < 196608) { int r = j2 / 1536, k = j2 - r * 1536;
        if (r < 80) v = *(const f32x4*)(xw + r * 1536 + k); }
      else {
        j2 -= 196608;
        if (j2 < 196608) { int r = j2 / 1536, k = j2 - r * 1536;
          if (r < 80) v = *(const f32x4*)(xwb + r * 1536 + k); }
        else {
          j2 -= 196608;
          if (j2 < 98304) { int d = j2 >> 6, k = j2 & 63;
            if (k < 48) v = *(const f32x4*)(dw + d * 48 + k); }
          else { j2 -= 98304; int d = j2 >> 6, k = j2 & 63;
            if (k < 48) v = *(const f32x4*)(dwb + d * 48 + k); }
        }
      }
    }
  }
  us4 o = { f2bf(v[0]), f2bf(v[1]), f2bf(v[2]), f2bf(v[3]) };
  *(us4*)wb = o;
}

// ===================== im2col =====================
__global__ __launch_bounds__(256) void im2col_v(const float* __restrict__ xv, ushort_t* __restrict__ Av)
{
  int i = blockIdx.x * 256 + threadIdx.x;
  if (i >= 1568 * 768) return;
  int m = i / 768, k = i % 768;
  int c = k >> 8, r = k & 255;
  int kh = r >> 4, kw = r & 15;
  int bt = m / 196, n = m % 196;
  int b = bt / TT, t = bt % TT;
  int hb = n / 14, wb = n % 14;
  Av[i] = f2bf(xv[(size_t)b * 602112 + (size_t)c * 200704 + t * 50176 + (hb * 16 + kh) * 224 + wb * 16 + kw]);
}

__global__ __launch_bounds__(256) void im2col_a(const float* __restrict__ xa, float* __restrict__ Aa)
{
  int i = blockIdx.x * 256 + threadIdx.x;
  if (i >= 192 * 256) return;
  int m = i / 256, k = i % 256;
  int kh = k >> 4, kw = k & 15;
  int b = m / 96, q = m % 96;
  int tb = q >> 2, fb = q & 3;
  Aa[i] = xa[(size_t)b * 24576 + (fb * 16 + kw) * 384 + tb * 16 + kh];
}

// ===================== assemble tokens + gather =====================
__global__ __launch_bounds__(256) void assemble_k(
    const float* __restrict__ tokv, const float* __restrict__ toka,
    const float* __restrict__ pos_v, const float* __restrict__ pos_a,
    const float* __restrict__ tpos_v, const float* __restrict__ tpos_a,
    const float* __restrict__ cls_v, const float* __restrict__ cls_a,
    const float* __restrict__ glob_v, const float* __restrict__ glob_a,
    const int* __restrict__ vis_idx,
    float* __restrict__ h, float* __restrict__ res)
{
  int i = blockIdx.x * 256 + threadIdx.x;
  if (i >= NROWS * DD) return;
  int d = i % DD;
  int bl = i / DD;
  int r = bl % LV, b = bl / LV;
  int tok = vis_idx[b * LV + r];
  int t = tok / 224, q = tok % 224;
  float v;
  if (q == 0) v = cls_v[d];
  else if (q <= 196) {
    int n = q - 1;
    v = tokv[((size_t)(b * TT + t) * 196 + n) * DD + d] + pos_v[n * DD + d] + tpos_v[t * DD + d];
  } else if (q == 197) v = glob_v[d];
  else if (q == 198) v = cls_a[d];
  else if (q <= 222) {
    int n = q - 199;
    v = toka[((size_t)b * 96 + t * 24 + n) * DD + d] + pos_a[n * DD + d] + tpos_a[t * DD + d];
  } else v = glob_a[d];
  h[i] = v;
  res[i] = 0.f;
}

// ============ fused (out-proj split-K reduce OR h read) + residual + RMSNorm ============
__global__ __launch_bounds__(256) void rmsnorm_k(
    const float* __restrict__ hsrc, const float* __restrict__ part,
    float* __restrict__ res, ushort_t* __restrict__ hn, const float* __restrict__ nw)
{
  int row = blockIdx.x;
  float* rp = res + (size_t)row * DD;
  ushort_t* op = hn + (size_t)row * DD;
  int tid = threadIdx.x;
  float v[3];
  float ss = 0.f;
#pragma unroll
  for (int i = 0; i < 3; ++i) {
    int c = tid + i * 256;
    float x;
    if (part) {
      x = part[(size_t)row * DD + c] + part[688128 + (size_t)row * DD + c]
        + part[2 * 688128 + (size_t)row * DD + c] + part[3 * 688128 + (size_t)row * DD + c];
    } else {
      x = hsrc[(size_t)row * DD + c];
    }
    x += rp[c];
    v[i] = x;
    ss += x * x;
  }
  for (int m = 1; m < 64; m <<= 1) ss += __shfl_xor(ss, m, 64);
  __shared__ float sred[4];
  if ((tid & 63) == 0) sred[tid >> 6] = ss;
  __syncthreads();
  float tot = sred[0] + sred[1] + sred[2] + sred[3];
  float sc = rsqrtf(tot / (float)DD + 1e-5f);
#pragma unroll
  for (int i = 0; i < 3; ++i) {
    int c = tid + i * 256;
    rp[c] = v[i];
    op[c] = f2bf(v[i] * sc * nw[c]);
  }
}

// ===================== causal depthwise conv (k=4, bf16 in) + silu -> bf16 =========
__global__ __launch_bounds__(256) void conv_k(
    const ushort_t* __restrict__ xz,
    const float* __restrict__ cw, const float* __restrict__ cb,
    const float* __restrict__ cwb, const float* __restrict__ cbb,
    ushort_t* __restrict__ xcFb, ushort_t* __restrict__ xcBb)
{
  int i = blockIdx.x * 256 + threadIdx.x;
  if (i >= NROWS * DI_) return;
  int d = i % DI_;
  int bl = i / DI_;
  int l = bl % LV, b = bl / LV;
  const ushort_t* xzb = xz + (size_t)b * LV * (2 * DI_);
  float accf = cb[d];
#pragma unroll
  for (int j = 0; j < 4; ++j) {
    int lp = l - 3 + j;
    if (lp >= 0) accf += bf2f(xzb[(size_t)lp * (2 * DI_) + d]) * cw[d * 4 + j];
  }
  float accb = cbb[d];
#pragma unroll
  for (int j = 0; j < 4; ++j) {
    int lp = l - 3 + j;
    if (lp >= 0) accb += bf2f(xzb[(size_t)(LV - 1 - lp) * (2 * DI_) + d]) * cwb[d * 4 + j];
  }
  xcFb[i] = f2bf(silu_f(accf));
  xcBb[i] = f2bf(silu_f(accb));
}

// ===================== split-K reduce (8 chunks) + dtr bf16 pack ==============
__global__ __launch_bounds__(256) void reduce_pack_k(
    const float* __restrict__ pF, const float* __restrict__ pB,
    float* __restrict__ prF, float* __restrict__ prB,
    ushort_t* __restrict__ dF, ushort_t* __restrict__ dB)
{
  int i = blockIdx.x * 256 + threadIdx.x;   // over 896*128
  if (i >= NROWS * 128) return;
  int dir = blockIdx.y;
  const float* part = dir ? pB : pF;
  float* proj = dir ? prB : prF;
  ushort_t* dtr = dir ? dB : dF;
  int row = i >> 7, col = i & 127;
  float s = 0.f;
  if (col < 80) {
#pragma unroll
    for (int c = 0; c < 8; ++c) s += part[c * (NROWS * 128) + i];
    proj[row * 80 + col] = s;
  }
  if (col < 64) dtr[(row << 6) + col] = f2bf(col < 48 ? s : 0.f);
}

// ===================== chunked selective scan =====================
__global__ __launch_bounds__(256) void scanA_k(
    const ushort_t* __restrict__ xcFb, const float* __restrict__ dtF, const float* __restrict__ prF,
    const ushort_t* __restrict__ xcBb, const float* __restrict__ dtB, const float* __restrict__ prB,
    const float* __restrict__ AlF, const float* __restrict__ AlB,
    float* __restrict__ hloc, float* __restrict__ Pb)
{
  int dir = blockIdx.z;
  const ushort_t* xc = dir ? xcBb : xcFb;
  const float* dt = dir ? dtB : dtF;
  const float* pr = dir ? prB : prF;
  const float* Al = dir ? AlB : AlF;
  int c = blockIdx.y;
  int g = blockIdx.x * 16 + (threadIdx.x >> 4);
  int n = threadIdx.x & 15;
  int b = g / DI_, d = g % DI_;
  float An = -__expf(Al[d * NS_ + n]);
  const ushort_t* xcp = xc + (size_t)b * LV * DI_ + d;
  const float* dtp = dt + (size_t)b * LV * DI_ + d;
  const float* prp = pr + (size_t)b * LV * 80;
  int l0 = c * CLEN;
  float hs = 0.f, S = 0.f;
  float dtv = dtp[(size_t)l0 * DI_];
  float xcv = bf2f(xcp[(size_t)l0 * DI_]);
  float bn  = prp[l0 * 80 + 48 + n];
  for (int kk = 0; kk < CLEN; ++kk) {
    float dtv_n = 0.f, xcv_n = 0.f, bn_n = 0.f;
    if (kk < CLEN - 1) {
      int l1 = l0 + kk + 1;
      dtv_n = dtp[(size_t)l1 * DI_];
      xcv_n = bf2f(xcp[(size_t)l1 * DI_]);
      bn_n  = prp[l1 * 80 + 48 + n];
    }
    hs = __expf(dtv * An) * hs + dtv * bn * xcv;
    S += dtv;
    dtv = dtv_n; xcv = xcv_n; bn = bn_n;
  }
  int idx = ((dir * 3072 + g) * 6 + c) * NS_ + n;
  hloc[idx] = hs;
  Pb[idx] = __expf(An * S);
}

// pass BC: both dirs in parallel warps; in-block h_start prefix; fused combine.
__global__ __launch_bounds__(256) void scanBC_k(
    const ushort_t* __restrict__ xcFb, const float* __restrict__ dtF, const float* __restrict__ prF,
    const ushort_t* __restrict__ xcBb, const float* __restrict__ dtB, const float* __restrict__ prB,
    const float* __restrict__ AlF, const float* __restrict__ AlB,
    const float* __restrict__ DpF, const float* __restrict__ DpB,
    const float* __restrict__ hloc, const float* __restrict__ Pb,
    const ushort_t* __restrict__ xz, ushort_t* __restrict__ yc)
{
  int c = blockIdx.y;                 // fwd chunk index
  int tid = threadIdx.x;
  int n = tid & 15, gi = (tid >> 4) & 7, dir = tid >> 7;
  int g = blockIdx.x * 8 + gi;
  int b = g / DI_, d = g % DI_;
  __shared__ float sbuf[2][8][64];

  const ushort_t* xc = dir ? xcBb : xcFb;
  const float* dt = dir ? dtB : dtF;
  const float* pr = dir ? prB : prF;
  const float* Al = dir ? AlB : AlF;
  const float* Dpp = dir ? DpB : DpF;
  int myc = dir ? (6 - c) : c;        // chunk in own time direction
  float An = -__expf(Al[d * NS_ + n]);
  float Dpd = Dpp[d];
  float hs = 0.f;
  for (int j = 0; j < myc; ++j) {
    int idx = ((dir * 3072 + g) * 6 + j) * NS_ + n;
    hs = Pb[idx] * hs + hloc[idx];
  }
  const ushort_t* xcp = xc + (size_t)b * LV * DI_ + d;
  const float* dtp = dt + (size_t)b * LV * DI_ + d;
  const float* prp = pr + (size_t)b * LV * 80;
  int l0 = myc * CLEN;
  float dtv = dtp[(size_t)l0 * DI_];
  float xcv = bf2f(xcp[(size_t)l0 * DI_]);
  float bn  = prp[l0 * 80 + 48 + n];
  float cn  = prp[l0 * 80 + 64 + n];
  for (int kk = 0; kk < CLEN; ++kk) {
    float dtv_n = 0.f, xcv_n = 0.f, bn_n = 0.f, cn_n = 0.f;
    if (kk < CLEN - 1) {
      int l1 = l0 + kk + 1;
      dtv_n = dtp[(size_t)l1 * DI_];
      xcv_n = bf2f(xcp[(size_t)l1 * DI_]);
      bn_n  = prp[l1 * 80 + 48 + n];
      cn_n  = prp[l1 * 80 + 64 + n];
    }
    hs = __expf(dtv * An) * hs + dtv * bn * xcv;
    float p = hs * cn;
    p += __shfl_xor(p, 1, 16);
    p += __shfl_xor(p, 2, 16);
    p += __shfl_xor(p, 4, 16);
    p += __shfl_xor(p, 8, 16);
    if (n == 0) {
      int off = dir ? (CLEN - 1 - kk) : kk;
      sbuf[dir][gi][off] = p + xcv * Dpd;
    }
    dtv = dtv_n; xcv = xcv_n; bn = bn_n; cn = cn_n;
  }
  __syncthreads();
  for (int oid = tid; oid < 512; oid += 256) {
    int gi2 = oid >> 6, kk = oid & 63;
    int g2 = blockIdx.x * 8 + gi2;
    int b2 = g2 / DI_, d2 = g2 % DI_;
    int l = c * CLEN + kk;
    float z = bf2f(xz[((size_t)b2 * LV + l) * 3072 + 1536 + d2]);
    float v = (sbuf[0][gi2][kk] + sbuf[1][gi2][kk]) * silu_f(z);
    yc[((size_t)b2 * LV + l) * DI_ + d2] = f2bf(v);
  }
}

// ===================== final: out = res + sum(partO) ==============
__global__ __launch_bounds__(256) void final_k(
    const float* __restrict__ res, const float* __restrict__ part, float* __restrict__ out)
{
  int i = blockIdx.x * 256 + threadIdx.x;
  if (i >= NROWS * DD) return;
  out[i] = res[i] + part[i] + part[688128 + i] + part[2 * 688128 + i] + part[3 * 688128 + i];
}

extern "C" void kernel_launch(void* const* d_in, const int* in_sizes, int n_in,
                              void* d_out, int out_size, void* d_ws, size_t ws_size,
                              hipStream_t stream)
{
  const float* x_v = (const float*)d_in[0];
  const float* x_a = (const float*)d_in[1];
  const float* patch_v_w = (const float*)d_in[2];
  const float* patch_v_b = (const float*)d_in[3];
  const float* patch_a_w = (const float*)d_in[4];
  const float* patch_a_b = (const float*)d_in[5];
  const float* pos_v = (const float*)d_in[6];
  const float* pos_a = (const float*)d_in[7];
  const float* tpos_v = (const float*)d_in[8];
  const float* tpos_a = (const float*)d_in[9];
  const float* cls_v = (const float*)d_in[10];
  const float* cls_a = (const float*)d_in[11];
  const float* glob_v = (const float*)d_in[12];
  const float* glob_a = (const float*)d_in[13];
  const float* norm_w = (const float*)d_in[14];
  const float* in_w = (const float*)d_in[15];
  const float* conv_w = (const float*)d_in[16];
  const float* conv_b = (const float*)d_in[17];
  const float* conv_w_b = (const float*)d_in[18];
  const float* conv_b_b = (const float*)d_in[19];
  const float* xproj_w = (const float*)d_in[20];
  const float* xproj_w_b = (const float*)d_in[21];
  const float *dt_w, *dt_bias, *dt_w_b, *dt_bias_b;
  if (in_sizes[23] == DEPTH_ * DI_ * RK_) {  // dict order: dt_w, dt_w_b, dt_b, dt_b_b
    dt_w = (const float*)d_in[22]; dt_w_b = (const float*)d_in[23];
    dt_bias = (const float*)d_in[24]; dt_bias_b = (const float*)d_in[25];
  } else {                                   // signature order
    dt_w = (const float*)d_in[22]; dt_bias = (const float*)d_in[23];
    dt_w_b = (const float*)d_in[24]; dt_bias_b = (const float*)d_in[25];
  }
  const float* A_log = (const float*)d_in[26];
  const float* A_log_b = (const float*)d_in[27];
  const float* D_par = (const float*)d_in[28];
  const float* D_par_b = (const float*)d_in[29];
  const float* out_w = (const float*)d_in[30];
  const int* vis_idx = (const int*)d_in[31];

  // ---------------- workspace layout (float units) ----------------
  float* ws = (float*)d_ws;
  float* res   = ws;                 // 688128
  float* hbuf  = ws + 688128;        // 688128 (phase-1 h only)
  float* R1    = ws + 1376256;       // 2752512: phase1 | xproj partials | hloc+Pb | outproj partials
  float* R2f   = ws + 4128768;       // 688128: hn_bf | dtrF/dtrB | ycb
  float* R3    = ws + 4816896;       // 1376256: xcFb + xcBb (bf16)
  float* xz    = ws + 7569408;       // holds 896*3072 bf16 (phase1: Av_bf alias)
  float* dtF   = ws + 10321920;      // 1376256
  float* dtB   = ws + 11698176;      // 1376256
  float* projF = ws + 13074432;      // 71680
  float* projB = ws + 13146112;      // 71680
  float* wPvf  = ws + 13217792;      // 294912 (589824 bf16)
  float* WALLf = ws + 13512704;      // 15*WLAYER ushorts = 30965760 floats

  // R1 views
  float* partF = R1;                         // 8*896*128 = 917504
  float* partB = R1 + 917504;
  float* hloc  = R1;                         // 589824
  float* Pb    = R1 + 589824;                // 589824
  float* partO = R1;                         // 4*688128 = 2752512
  // phase-1 views
  float* tokv  = R1;                         // 1568*768
  float* toka  = R1 + 1204224;               // 192*768
  float* Aa    = R1 + 1351680;               // 192*256
  ushort_t* Av_bf = (ushort_t*)xz;           // 1568*768 bf16
  ushort_t* wPv   = (ushort_t*)wPvf;
  // R2 views
  ushort_t* hn_bf = (ushort_t*)R2f;          // 896*768
  ushort_t* dtrF  = (ushort_t*)R2f;          // 896*64
  ushort_t* dtrB  = ((ushort_t*)R2f) + 57344;
  ushort_t* ycb   = (ushort_t*)R2f;          // 896*1536
  // R3 views
  ushort_t* xcFb = (ushort_t*)R3;            // 896*1536
  ushort_t* xcBb = ((ushort_t*)R3) + 1376256;
  ushort_t* xzb  = (ushort_t*)xz;            // 896*3072 bf16

  size_t need_big = ((size_t)13512704 + 30965760) * 4;
  int bigws = ws_size >= need_big;
  ushort_t* WALL = (ushort_t*)WALLf;

  dim3 blk(256);

  // ---- weight pre-cast: all 15 live layers, vectorized ----
  if (bigws)
    cast_all4_k<<<(NRUN * WL4 + 255) / 256, blk, 0, stream>>>(
        in_w, out_w, xproj_w, xproj_w_b, dt_w, dt_w_b, WALL, NRUN);

  // ---- phase 1: patch embed + assemble ----
  im2col_v<<<4704, blk, 0, stream>>>(x_v, Av_bf);
  cast4_k<<<576, blk, 0, stream>>>(patch_v_w, wPv, 147456);
  im2col_a<<<192, blk, 0, stream>>>(x_a, Aa);
  mfma_gemm<<<dim3(6, 13, 1), blk, 0, stream>>>(Av_bf, nullptr, 768, wPv, nullptr, 768,
                                                patch_v_b, nullptr, tokv, nullptr, 768,
                                                1568, 768, 1, 0, 0);
  gemm_nt<<<dim3(12, 3, 1), blk, 0, stream>>>(Aa, 256, patch_a_w, 256, patch_a_b,
                                              toka, 768, 192, 768, 256);
  assemble_k<<<2688, blk, 0, stream>>>(tokv, toka, pos_v, pos_a, tpos_v, tpos_a,
                                       cls_v, cls_a, glob_v, glob_a, vis_idx, hbuf, res);

  // ---- phase 2: layers 0..14 (layer 15's compute is dead except res += h) ----
  for (int l = 0; l < NRUN; ++l) {
    const float* nw  = norm_w + l * DD;
    const float* cw  = conv_w + l * DI_ * KC_;
    const float* cb  = conv_b + l * DI_;
    const float* cwb = conv_w_b + l * DI_ * KC_;
    const float* cbb = conv_b_b + l * DI_;
    const float* dbi = dt_bias + l * DI_;
    const float* dbib = dt_bias_b + l * DI_;
    const float* al  = A_log + (size_t)l * DI_ * NS_;
    const float* alb = A_log_b + (size_t)l * DI_ * NS_;
    const float* dp  = D_par + l * DI_;
    const float* dpb = D_par_b + l * DI_;

    ushort_t* wb = bigws ? (WALL + (size_t)l * WLAYER) : WALL;
    if (!bigws)
      cast_all4_k<<<(WL4 + 255) / 256, blk, 0, stream>>>(
          in_w + (size_t)l * 2359296, out_w + (size_t)l * 1179648,
          xproj_w + (size_t)l * 122880, xproj_w_b + (size_t)l * 122880,
          dt_w + (size_t)l * 73728, dt_w_b + (size_t)l * 73728, wb, 1);
    ushort_t* wIn  = wb;
    ushort_t* wOut = wIn + 2359296;
    ushort_t* wXF  = wOut + 1179648;
    ushort_t* wXB  = wXF + 196608;
    ushort_t* wDF  = wXB + 196608;
    ushort_t* wDB  = wDF + 98304;

    // residual add + RMSNorm (fuses previous layer's out-proj split-K reduce)
    rmsnorm_k<<<NROWS, blk, 0, stream>>>(hbuf, l ? partO : nullptr, res, hn_bf, nw);
    // in-proj: [896,3072] = hn @ in_w^T, bf16 out
    mfma_gemm<<<dim3(24, 7, 1), blk, 0, stream>>>(hn_bf, nullptr, 768, wIn, nullptr, 768,
                                                  nullptr, nullptr, (float*)xzb, nullptr, 3072,
                                                  NROWS, 768, 1, 0, 2);
    conv_k<<<5376, blk, 0, stream>>>(xzb, cw, cb, cwb, cbb, xcFb, xcBb);
    // xproj both dirs, split-K x8
    mfma_gemm<<<dim3(1, 7, 16), blk, 0, stream>>>(xcFb, xcBb, 1536, wXF, wXB, 1536,
                                                  nullptr, nullptr, partF, partB, 128,
                                                  NROWS, 1536, 8, NROWS * 128, 0);
    reduce_pack_k<<<dim3(448, 2, 1), blk, 0, stream>>>(partF, partB, projF, projB, dtrF, dtrB);
    // dt both dirs: softplus(dtr @ dtw^T + b), f32 out
    mfma_gemm<<<dim3(12, 7, 2), blk, 0, stream>>>(dtrF, dtrB, 64, wDF, wDB, 64,
                                                  dbi, dbib, dtF, dtB, 1536,
                                                  NROWS, 64, 1, 0, 1);
    // chunked scan: passA then fused passB+combine
    scanA_k<<<dim3(192, 6, 2), blk, 0, stream>>>(xcFb, dtF, projF, xcBb, dtB, projB,
                                                 al, alb, hloc, Pb);
    scanBC_k<<<dim3(384, NCH, 1), blk, 0, stream>>>(xcFb, dtF, projF, xcBb, dtB, projB,
                                                    al, alb, dp, dpb, hloc, Pb, xzb, ycb);
    // out-proj split-K x4: partials reduced by next layer's rmsnorm (or final_k)
    mfma_gemm<<<dim3(6, 7, 4), blk, 0, stream>>>(ycb, nullptr, 1536, wOut, nullptr, 1536,
                                                 nullptr, nullptr, partO, nullptr, 768,
                                                 NROWS, 1536, 4, NROWS * DD, 0);
  }

  final_k<<<2688, blk, 0, stream>>>(res, partO, (float*)d_out);
}